// Round 7
// baseline (418.623 us; speedup 1.0000x reference)
//
#include <hip/hip_runtime.h>
#include <stdint.h>

typedef short s8v __attribute__((ext_vector_type(8)));
typedef float f4v __attribute__((ext_vector_type(4)));
typedef unsigned short u16;

#define MFMA16(a, b, c) __builtin_amdgcn_mfma_f32_16x16x32_bf16(a, b, c, 0, 0, 0)
#define SCALE 0.1889822365046136f

__device__ __forceinline__ u16 f2bf(float f) {
  union { float f; uint32_t u; } v;
  v.f = f;
  uint32_t u = v.u;
  u += 0x7fffu + ((u >> 16) & 1u);   // RNE
  return (u16)(u >> 16);
}

__device__ __forceinline__ void gld_lds16(const void* g, void* l) {
  __builtin_amdgcn_global_load_lds(
      (const __attribute__((address_space(1))) void*)g,
      (__attribute__((address_space(3))) void*)l, 16, 0, 0);
}

// ---------------------------------------------------------------------------
// prep: x f32 -> bf16 (restored: streaming cast at full BW beats in-kernel
// cast, R6 post-mortem); pack W^T for QKV (768x224, zero-padded rows) and
// Wout (256x224, zero-padded rows) as bf16 [n][k].
// ---------------------------------------------------------------------------
__global__ void prep_kernel(const float4* __restrict__ x4,
                            const float* __restrict__ Wq,
                            const float* __restrict__ Wkv,
                            const float* __restrict__ Wout,
                            u16* __restrict__ xb,
                            u16* __restrict__ wqkvt,
                            u16* __restrict__ woutt) {
  const int gsz = gridDim.x * blockDim.x;
  const int gt = blockIdx.x * blockDim.x + threadIdx.x;
  for (int i = gt; i < 7340032; i += gsz) {   // 29360128/4
    float4 v = x4[i];
    ushort4 o;
    o.x = f2bf(v.x); o.y = f2bf(v.y); o.z = f2bf(v.z); o.w = f2bf(v.w);
    ((ushort4*)xb)[i] = o;
  }
  for (int i = gt; i < 768 * 224; i += gsz) {
    const int n = i / 224, k = i - n * 224;
    float v = 0.f;
    if (n < 224) v = Wq[k * 224 + n];
    else if (n < 672) v = Wkv[k * 448 + (n - 224)];
    wqkvt[i] = f2bf(v);
  }
  for (int i = gt; i < 256 * 224; i += gsz) {
    const int n = i / 224, k = i - n * 224;
    const float v = (n < 224) ? Wout[k * 224 + n] : 0.f;
    woutt[i] = f2bf(v);
  }
}

// ---------------------------------------------------------------------------
// Stream-both GEMM: C[M][N] = A[M][224] * Bt[N][224]^T, bf16 in.
// One block per (m-tile, n-tile); 1D grid with bijective XCD-chunked swizzle
// so all NT n-tiles of an m-tile run consecutively ON THE SAME XCD -> the A
// tile is HBM-fetched once and L2-shared by its NT readers (A-reuse via L2,
// not LDS persistence — R6 lesson: the 56KB persistent A-tile halved
// occupancy and cost more than the fetch it saved).
// A and B both [128][32] gld_lds subtiles, double-buffered, distance-2
// prefetch, ONE barrier per K-step, 7 steps.
// LDS = 4 x 8192 = 32768 B -> 4-5 blocks/CU (VGPR ~120 -> 4).
// OUT_F32=0: store bf16. OUT_F32=1: store f32 + bias.
// ---------------------------------------------------------------------------
template <int OUT_F32, int NT>
__global__ __launch_bounds__(256) void gemm_st(const u16* __restrict__ A,
                                               const u16* __restrict__ Bt,
                                               void* __restrict__ Cp,
                                               const float* __restrict__ bias,
                                               int Nvalid, int ldc, int cpx) {
  extern __shared__ u16 smem[];
  u16* As0 = smem;            // [128][32] = 8192 B each
  u16* As1 = smem + 4096;
  u16* Bs0 = smem + 8192;
  u16* Bs1 = smem + 12288;
  const int tid = threadIdx.x;
  const int wave = tid >> 6, lane = tid & 63;
  const int c16 = lane & 15, g = lane >> 4;
  const int wm = wave & 1, wn = wave >> 1;

  // bijective XCD swizzle (grid % 8 == 0): XCD k owns works [k*cpx, (k+1)*cpx)
  const int bid = blockIdx.x;
  const int work = (bid & 7) * cpx + (bid >> 3);
  const int mt = work / NT;
  const int nt = work - mt * NT;
  const int m0 = mt * 128, n0 = nt * 128;

  // staging geometry: subtile = 128 rows x 64 B; lane's byte = wave*1024+lane*16
  const int fbw = wave * 1024 + lane * 16;
  const int brow0 = fbw >> 6, bcol0 = (fbw & 63) >> 1;

#define STAGE(Base, rtile, ktile, bufp)                                        \
  do {                                                                         \
    char* bb = (char*)(bufp) + wave * 1024;                                    \
    const u16* src =                                                           \
        (Base) + (size_t)((rtile) * 128 + brow0) * 224 + (ktile) * 32 + bcol0; \
    gld_lds16(src, bb);                                                        \
    gld_lds16(src + (size_t)64 * 224, bb + 4096);                              \
  } while (0)

  STAGE(A, mt, 0, As0);
  STAGE(Bt, nt, 0, Bs0);
  STAGE(A, mt, 1, As1);
  STAGE(Bt, nt, 1, Bs1);
  __syncthreads();           // drains step-0 and step-1 staging

  f4v acc[4][4] = {};
  for (int kt = 0; kt < 7; ++kt) {
    const u16* Asc = (kt & 1) ? As1 : As0;
    const u16* Bsc = (kt & 1) ? Bs1 : Bs0;
    s8v af[4], bf[4];
    for (int tt = 0; tt < 4; ++tt)
      af[tt] = *(const s8v*)&Asc[(wm * 64 + tt * 16 + c16) * 32 + g * 8];
    for (int tt = 0; tt < 4; ++tt)
      bf[tt] = *(const s8v*)&Bsc[(wn * 64 + tt * 16 + c16) * 32 + g * 8];
    for (int i = 0; i < 4; ++i)
      for (int j = 0; j < 4; ++j)
        acc[i][j] = MFMA16(af[i], bf[j], acc[i][j]);
    if (kt < 6) {
      __syncthreads();       // stage(kt+1) already latency-covered; buf free
      if (kt + 2 < 7) {
        STAGE(A, mt, kt + 2, (kt & 1) ? As1 : As0);
        STAGE(Bt, nt, kt + 2, (kt & 1) ? Bs1 : Bs0);
      }
    }
  }

  for (int i = 0; i < 4; ++i) {
    const int rowb = m0 + wm * 64 + i * 16 + g * 4;
    for (int j = 0; j < 4; ++j) {
      const int col = n0 + wn * 64 + j * 16 + c16;
      if (col < Nvalid) {
        if (OUT_F32) {
          const float bz = bias[col];
          for (int r = 0; r < 4; ++r)
            ((float*)Cp)[(size_t)(rowb + r) * ldc + col] = acc[i][j][r] + bz;
        } else {
          for (int r = 0; r < 4; ++r)
            ((u16*)Cp)[(size_t)(rowb + r) * ldc + col] = f2bf(acc[i][j][r]);
        }
      }
    }
  }
#undef STAGE
}

// ---------------------------------------------------------------------------
// Branch 1 body: local window attention (R6 version — division-light,
// conflict-free V staging). One block per (b, window); wave = head.
// ---------------------------------------------------------------------------
__device__ __forceinline__ void attn_local_body(u16* sm, int blk, int tid,
                                                const u16* __restrict__ qkv,
                                                const float* __restrict__ pos1,
                                                u16* __restrict__ attn) {
  u16* qs = sm;           // 8192 shorts
  u16* ks = sm + 8192;    // 8192 shorts
  u16* vt = sm + 18432;   // 9216 shorts
  u16* pm = sm;           // 18432 shorts, aliases qs+ks
  const int b = blk >> 4, win = blk & 15;
  const int wy = win >> 2, wx = win & 3;
  const int base_s = (b * 32 + wy * 8) * 32 + wx * 8;
  // stage q,k: 3584 ushort4, idx = mtx*1792 + h*448 + t*7 + c4
#pragma unroll
  for (int m = 0; m < 14; ++m) {
    const int idx = m * 256 + tid;
    const int q7 = idx / 7;              // = mtx*256 + h*64 + t (magic-mul)
    const int c4 = idx - q7 * 7;
    const int t = q7 & 63, h = (q7 >> 6) & 3, mtx = q7 >> 8;
    const int s = base_s + (t >> 3) * 32 + (t & 7);
    const ushort4 v = *(const ushort4*)(qkv + (size_t)s * 672 + mtx * 224 + h * 28 + c4 * 4);
    *(ushort4*)((mtx ? ks : qs) + (h * 64 + t) * 32 + c4 * 4) = v;
  }
  // zero k-pad cols 28..31 of q,k
#pragma unroll
  for (int m = 0; m < 2; ++m) {
    const int idx = m * 256 + tid;
    const int mtx = idx >> 8;
    const int h = (idx >> 6) & 3, t = idx & 63;
    const ushort4 z = {0, 0, 0, 0};
    *(ushort4*)((mtx ? ks : qs) + (h * 64 + t) * 32 + 28) = z;
  }
  // stage v transposed -> vt[h][d][t]; lane = t, head = wave, loop c4.
  {
    const int t = tid & 63, wq = tid >> 6;
    const int s = base_s + (t >> 3) * 32 + (t & 7);
    const u16* vrow = qkv + (size_t)s * 672 + 448 + wq * 28;
    u16* vcolbase = vt + (wq * 32) * 72 + t;
#pragma unroll
    for (int c4 = 0; c4 < 7; ++c4) {
      const ushort4 v = *(const ushort4*)(vrow + c4 * 4);
      u16* col = vcolbase + (c4 * 4) * 72;
      col[0] = v.x; col[72] = v.y; col[144] = v.z; col[216] = v.w;
    }
  }
  __syncthreads();
  const int h = tid >> 6, lane = tid & 63;
  const int c16 = lane & 15, g = lane >> 4;
  s8v af[4], bf[4];
  for (int t = 0; t < 4; ++t) af[t] = *(const s8v*)&qs[(h * 64 + t * 16 + c16) * 32 + g * 8];
  for (int t = 0; t < 4; ++t) bf[t] = *(const s8v*)&ks[(h * 64 + t * 16 + c16) * 32 + g * 8];
  const f4v fz = {0.f, 0.f, 0.f, 0.f};
  f4v sc[4][4];
  for (int i = 0; i < 4; ++i)
    for (int j = 0; j < 4; ++j)
      sc[i][j] = MFMA16(af[i], bf[j], fz);
  float lrow[4][4];
  const float* ph = pos1 + h * 4096;
  for (int i = 0; i < 4; ++i) {
    for (int r = 0; r < 4; ++r) {
      const int irow = i * 16 + g * 4 + r;
      float mx = -1e30f;
      for (int j = 0; j < 4; ++j) {
        const float v = sc[i][j][r] * SCALE + ph[irow * 64 + j * 16 + c16];
        sc[i][j][r] = v;
        mx = fmaxf(mx, v);
      }
      for (int d = 1; d < 16; d <<= 1) mx = fmaxf(mx, __shfl_xor(mx, d, 64));
      float sum = 0.f;
      for (int j = 0; j < 4; ++j) {
        const float e = __expf(sc[i][j][r] - mx);
        sc[i][j][r] = e;
        sum += e;
      }
      for (int d = 1; d < 16; d <<= 1) sum += __shfl_xor(sum, d, 64);
      lrow[i][r] = sum;
    }
  }
  __syncthreads();   // qs/ks frag reads done before pm (aliased) written
  for (int i = 0; i < 4; ++i)
    for (int r = 0; r < 4; ++r) {
      const int irow = i * 16 + g * 4 + r;
      for (int j = 0; j < 4; ++j)
        pm[(h * 64 + irow) * 72 + j * 16 + c16] = f2bf(sc[i][j][r]);
    }
  f4v o[4][2] = {};
  for (int kk = 0; kk < 2; ++kk) {
    s8v ap[4], bv[2];
    for (int t = 0; t < 4; ++t)
      ap[t] = *(const s8v*)&pm[(h * 64 + t * 16 + c16) * 72 + kk * 32 + g * 8];
    for (int t = 0; t < 2; ++t)
      bv[t] = *(const s8v*)&vt[(h * 32 + t * 16 + c16) * 72 + kk * 32 + g * 8];
    for (int i = 0; i < 4; ++i)
      for (int j = 0; j < 2; ++j)
        o[i][j] = MFMA16(ap[i], bv[j], o[i][j]);
  }
  for (int i = 0; i < 4; ++i)
    for (int r = 0; r < 4; ++r) {
      const int irow = i * 16 + g * 4 + r;
      const int s = base_s + (irow >> 3) * 32 + (irow & 7);
      const float inv = 1.f / lrow[i][r];
      for (int j = 0; j < 2; ++j) {
        const int d = j * 16 + c16;
        if (d < 28)
          attn[(size_t)s * 224 + h * 28 + d] = f2bf(o[i][j][r] * inv);
      }
    }
}

// ---------------------------------------------------------------------------
// Branch 2 body: cross-window attention (R6 version — padded vt stride,
// division-light staging).
// ---------------------------------------------------------------------------
__device__ __forceinline__ void attn_global_body(u16* smg, int blk, int tid,
                                                 const u16* __restrict__ qkv,
                                                 const float* __restrict__ pos2,
                                                 u16* __restrict__ attn) {
  u16* qs = smg;            // [4][4][16][32] = 8192 u16
  u16* ks = smg + 8192;
  u16* vt = smg + 16384;    // [4] w-stride 2056: [4][32][16] + 8 pad
  u16* p2 = smg + 24608;    // [4][16][32]
  const int b = blk >> 4, ig = blk & 15;
  // ---- stage q,k: 3584 ushort4, idx = seg*1792 + (w*16+j)*28 + hq*7 + d4
#pragma unroll
  for (int m = 0; m < 14; ++m) {
    const int idx = m * 256 + tid;
    const int q7 = idx / 7;              // = seg*256 + (w*16+j)*4 + hq
    const int d4 = idx - q7 * 7;
    const int hq = q7 & 3, row = (q7 >> 2) & 63, seg = q7 >> 8;
    const int w = row >> 4, j = row & 15;
    const int ii = ig * 4 + w;
    const int y = ii >> 3, x = ii & 7;
    const int s = (b * 32 + (j >> 2) * 8 + y) * 32 + (j & 3) * 8 + x;
    const ushort4 v =
        *(const ushort4*)(qkv + (size_t)s * 672 + 112 + seg * 224 + hq * 28 + d4 * 4);
    *(ushort4*)((seg ? ks : qs) + ((w * 4 + hq) * 16 + j) * 32 + d4 * 4) = v;
  }
  // ---- stage v transposed: lane=(w,j), loop c4 = wq..27 step 4
  {
    const int j = tid & 15, w = (tid >> 4) & 3, wq = tid >> 6;
    const int ii = ig * 4 + w;
    const int y = ii >> 3, x = ii & 7;
    const int s = (b * 32 + (j >> 2) * 8 + y) * 32 + (j & 3) * 8 + x;
    const u16* vrow = qkv + (size_t)s * 672 + 560;
    u16* vbase = vt + w * 2056 + j;
#pragma unroll
    for (int c4o = 0; c4o < 7; ++c4o) {
      const int c4 = c4o * 4 + wq;       // 0..27
      const int hq = c4 / 7;             // magic-mul
      const int d4 = c4 - hq * 7;
      const ushort4 v = *(const ushort4*)(vrow + c4 * 4);
      u16* col = vbase + (hq * 32 + d4 * 4) * 16;
      col[0] = v.x; col[16] = v.y; col[32] = v.z; col[48] = v.w;
    }
  }
  // zero d-pad 28..31 of qs/ks and vt rows 28..31
#pragma unroll
  for (int m = 0; m < 2; ++m) {
    const int idx = m * 256 + tid;
    const ushort4 z = {0, 0, 0, 0};
    *(ushort4*)(((idx & 256) ? ks : qs) + (idx & 255) * 32 + 28) = z;
  }
  {
    const ushort4 z = {0, 0, 0, 0};
    const int w = tid >> 6, hq = (tid >> 4) & 3;
    const int dd = 28 + ((tid >> 2) & 3), j4 = tid & 3;
    *(ushort4*)(vt + w * 2056 + (hq * 32 + dd) * 16 + j4 * 4) = z;
  }
  __syncthreads();
  const int w = tid >> 6, lane = tid & 63;
  const int c16 = lane & 15, g = lane >> 4;
  const int i = ig * 4 + w;
  const int y = i >> 3, x = i & 7;
  const int w4 = w * 4;
  const f4v fz = {0.f, 0.f, 0.f, 0.f};
  for (int h = 0; h < 4; ++h) {
    const s8v aq = *(const s8v*)&qs[((w4 + h) * 16 + c16) * 32 + g * 8];
    const s8v bk = *(const s8v*)&ks[((w4 + h) * 16 + c16) * 32 + g * 8];
    const f4v s = MFMA16(aq, bk, fz);
    const float* ph = pos2 + h * 256;
    float l[4];
    for (int r = 0; r < 4; ++r) {
      const float v = s[r] * SCALE + ph[(g * 4 + r) * 16 + c16];
      float mx = v;
      for (int d = 1; d < 16; d <<= 1) mx = fmaxf(mx, __shfl_xor(mx, d, 64));
      const float e = __expf(v - mx);
      float sum = e;
      for (int d = 1; d < 16; d <<= 1) sum += __shfl_xor(sum, d, 64);
      l[r] = sum;
      p2[(w * 16 + g * 4 + r) * 32 + c16] = f2bf(e);
      p2[(w * 16 + g * 4 + r) * 32 + c16 + 16] = 0;   // K pad
    }
    const s8v ap = *(const s8v*)&p2[(w * 16 + c16) * 32 + g * 8];  // same-wave RAW
    f4v o[2];
    for (int nt = 0; nt < 2; ++nt) {
      s8v bv = {0, 0, 0, 0, 0, 0, 0, 0};
      if (g < 2)
        bv = *(const s8v*)&vt[w * 2056 + (h * 32 + nt * 16 + c16) * 16 + g * 8];
      o[nt] = MFMA16(ap, bv, fz);
    }
    for (int nt = 0; nt < 2; ++nt)
      for (int r = 0; r < 4; ++r) {
        const int d = nt * 16 + c16;
        if (d < 28) {
          const int wi = g * 4 + r;
          const int sw = (b * 32 + (wi >> 2) * 8 + y) * 32 + (wi & 3) * 8 + x;
          attn[(size_t)sw * 224 + 112 + h * 28 + d] = f2bf(o[nt][r] / l[r]);
        }
      }
  }
}

// ---------------------------------------------------------------------------
// Fused attention: blocks 0..2047 = local windows, 2048..4095 = cross-window.
// LDS = 55296 -> 2 blocks/CU.
// ---------------------------------------------------------------------------
__global__ __launch_bounds__(256) void attn_fused(const u16* __restrict__ qkv,
                                                  const float* __restrict__ pos1,
                                                  const float* __restrict__ pos2,
                                                  u16* __restrict__ attn) {
  extern __shared__ u16 sm[];
  const int blk = blockIdx.x;
  const int tid = threadIdx.x;
  if (blk < 2048)
    attn_local_body(sm, blk, tid, qkv, pos1, attn);
  else
    attn_global_body(sm, blk - 2048, tid, qkv, pos2, attn);
}

// ---------------------------------------------------------------------------
// ws layout (bytes):
//   qkv   @ 0          : 131072*672*2 = 176,160,768
//   xb    @ 176160768  : 131072*224*2 =  58,720,256  (reused as attn buffer)
//   wqkvt @ 234881024  : 768*224*2    =     344,064
//   woutt @ 235225088  : 256*224*2    =     114,688
// ---------------------------------------------------------------------------
extern "C" void kernel_launch(void* const* d_in, const int* in_sizes, int n_in,
                              void* d_out, int out_size, void* d_ws, size_t ws_size,
                              hipStream_t stream) {
  const float* x    = (const float*)d_in[0];
  const float* Wq   = (const float*)d_in[1];
  const float* Wkv  = (const float*)d_in[2];
  const float* Wout = (const float*)d_in[3];
  const float* bout = (const float*)d_in[4];
  const float* pos1 = (const float*)d_in[5];
  const float* pos2 = (const float*)d_in[6];
  char* ws = (char*)d_ws;
  u16* qkv   = (u16*)ws;
  u16* xb    = (u16*)(ws + 176160768);
  u16* attn  = xb;                        // qkv consumed before attn written
  u16* wqkvt = (u16*)(ws + 234881024);
  u16* woutt = (u16*)(ws + 235225088);

  prep_kernel<<<dim3(1024), 256, 0, stream>>>(
      (const float4*)x, Wq, Wkv, Wout, xb, wqkvt, woutt);

  // qkv = x @ [Wq|Wkv]: 1024 m-tiles x 6 n-tiles = 6144 blocks, cpx = 768
  gemm_st<0, 6><<<dim3(6144), 256, 32768, stream>>>(
      xb, wqkvt, qkv, nullptr, 672, 672, 768);

  attn_fused<<<dim3(4096), 256, 55296, stream>>>(qkv, pos1, pos2, attn);

  // out = attn @ Wout + bout: 1024 x 2 = 2048 blocks, cpx = 256
  gemm_st<1, 2><<<dim3(2048), 256, 32768, stream>>>(
      attn, woutt, d_out, bout, 224, 224, 256);
}

// Round 8
// 395.223 us; speedup vs baseline: 1.0592x; 1.0592x over previous
//
#include <hip/hip_runtime.h>
#include <stdint.h>

typedef short s8v __attribute__((ext_vector_type(8)));
typedef float f4v __attribute__((ext_vector_type(4)));
typedef unsigned short u16;

#define MFMA16(a, b, c) __builtin_amdgcn_mfma_f32_16x16x32_bf16(a, b, c, 0, 0, 0)
#define SCALE 0.1889822365046136f

__device__ __forceinline__ u16 f2bf(float f) {
  union { float f; uint32_t u; } v;
  v.f = f;
  uint32_t u = v.u;
  u += 0x7fffu + ((u >> 16) & 1u);   // RNE
  return (u16)(u >> 16);
}

__device__ __forceinline__ void gld_lds16(const void* g, void* l) {
  __builtin_amdgcn_global_load_lds(
      (const __attribute__((address_space(1))) void*)g,
      (__attribute__((address_space(3))) void*)l, 16, 0, 0);
}

__device__ __forceinline__ s8v mk8(ushort4 lo, ushort4 hi) {
  s8v r;
  r[0] = (short)lo.x; r[1] = (short)lo.y; r[2] = (short)lo.z; r[3] = (short)lo.w;
  r[4] = (short)hi.x; r[5] = (short)hi.y; r[6] = (short)hi.z; r[7] = (short)hi.w;
  return r;
}

// ---------------------------------------------------------------------------
// prep: weights only (x cast fused into gemm1's A staging) — R6 config.
// ---------------------------------------------------------------------------
__global__ void prep_kernel(const float* __restrict__ Wq,
                            const float* __restrict__ Wkv,
                            const float* __restrict__ Wout,
                            u16* __restrict__ wqkvt,
                            u16* __restrict__ woutt) {
  const int gsz = gridDim.x * blockDim.x;
  const int gt = blockIdx.x * blockDim.x + threadIdx.x;
  for (int i = gt; i < 768 * 224; i += gsz) {
    const int n = i / 224, k = i - n * 224;
    float v = 0.f;
    if (n < 224) v = Wq[k * 224 + n];
    else if (n < 672) v = Wkv[k * 448 + (n - 224)];
    wqkvt[i] = f2bf(v);
  }
  for (int i = gt; i < 256 * 224; i += gsz) {
    const int n = i / 224, k = i - n * 224;
    const float v = (n < 224) ? Wout[k * 224 + n] : 0.f;
    woutt[i] = f2bf(v);
  }
}

// ---------------------------------------------------------------------------
// A-persistent GEMM (R6, unchanged — best measured): C = A[M][224] * Bt^T.
// ---------------------------------------------------------------------------
template <int A_F32, int OUT_F32, int NTILES>
__global__ __launch_bounds__(256) void gemm_af(const void* __restrict__ Ap,
                                               const u16* __restrict__ Bt,
                                               void* __restrict__ Cp,
                                               const float* __restrict__ bias,
                                               int Nvalid, int ldc) {
  extern __shared__ u16 smem[];
  u16* As  = smem;            // [128][224] = 57344 B
  u16* Bs0 = smem + 28672;    // [128][32] = 8192 B
  u16* Bs1 = smem + 32768;
  const int tid = threadIdx.x;
  const int wave = tid >> 6, lane = tid & 63;
  const int c16 = lane & 15, g = lane >> 4;
  const int m0 = blockIdx.x * 128;
  const int wm = wave & 1, wn = wave >> 1;

  const int fbw = wave * 1024 + lane * 16;
  const int brow0 = fbw >> 6, bcol0 = (fbw & 63) >> 1;

#define STAGE_B(ntile, ktile, bufp)                                            \
  do {                                                                         \
    char* bb = (char*)((bufp) ? Bs1 : Bs0) + wave * 1024;                      \
    const u16* src =                                                           \
        Bt + (size_t)((ntile) * 128 + brow0) * 224 + (ktile) * 32 + bcol0;     \
    gld_lds16(src, bb);                                                        \
    gld_lds16(src + (size_t)64 * 224, bb + 4096);                              \
  } while (0)

  STAGE_B(0, 0, 0);
  if (NTILES * 7 > 1) STAGE_B(0, 1, 1);

  if (A_F32) {
    const float* Af = (const float*)Ap + (size_t)m0 * 224;
#pragma unroll
    for (int rnd = 0; rnd < 28; ++rnd) {
      const int e0 = rnd * 1024 + tid * 4;
      const float4 v = *(const float4*)(Af + e0);
      ushort4 o;
      o.x = f2bf(v.x); o.y = f2bf(v.y); o.z = f2bf(v.z); o.w = f2bf(v.w);
      *(ushort4*)(As + e0) = o;
    }
  } else {
    for (int rnd = 0; rnd < 14; ++rnd) {
      const int fb = rnd * 4096 + fbw;
      const int row = fb / 448;
      const int off = fb - row * 448;
      gld_lds16((const u16*)Ap + (size_t)(m0 + row) * 224 + (off >> 1),
                (char*)As + rnd * 4096 + wave * 1024);
    }
  }

  __syncthreads();

  for (int nt = 0; nt < NTILES; ++nt) {
    f4v acc[4][4] = {};
    for (int kt = 0; kt < 7; ++kt) {
      const int t = nt * 7 + kt;
      const u16* Bs = (t & 1) ? Bs1 : Bs0;
      s8v af[4], bf[4];
      for (int tt = 0; tt < 4; ++tt)
        af[tt] = *(const s8v*)&As[(wm * 64 + tt * 16 + c16) * 224 + kt * 32 + g * 8];
      for (int tt = 0; tt < 4; ++tt)
        bf[tt] = *(const s8v*)&Bs[(wn * 64 + tt * 16 + c16) * 32 + g * 8];
      for (int i = 0; i < 4; ++i)
        for (int j = 0; j < 4; ++j)
          acc[i][j] = MFMA16(af[i], bf[j], acc[i][j]);
      __syncthreads();
      const int ns = t + 2;
      if (ns < NTILES * 7) {
        const int nnt = ns / 7;
        STAGE_B(nnt, ns - nnt * 7, t & 1);
      }
    }
    const int n0 = nt * 128;
    for (int i = 0; i < 4; ++i) {
      const int rowb = m0 + wm * 64 + i * 16 + g * 4;
      for (int j = 0; j < 4; ++j) {
        const int col = n0 + wn * 64 + j * 16 + c16;
        if (col < Nvalid) {
          if (OUT_F32) {
            const float bz = bias[col];
            for (int r = 0; r < 4; ++r)
              ((float*)Cp)[(size_t)(rowb + r) * ldc + col] = acc[i][j][r] + bz;
          } else {
            for (int r = 0; r < 4; ++r)
              ((u16*)Cp)[(size_t)(rowb + r) * ldc + col] = f2bf(acc[i][j][r]);
          }
        }
      }
    }
  }
#undef STAGE_B
}

// ---------------------------------------------------------------------------
// Branch 1 body v3: local window attention, LDS diet for 4 blocks/CU.
//  - Q: direct global->reg fragments (no qs buffer): 8 x 8B loads/thread,
//    issued BEFORE the staging barrier; g==3 upper half zero (K-pad 28..31).
//  - P: pm [4][64][40], written/consumed in TWO 32-col passes (kk halves).
//  - ks [4][64][32] aliases pm's first 8192 u16 (consumed before pm write).
//  - vt [4][32][72] at +10240.  Total 19456 u16 = 38912 B.
// ---------------------------------------------------------------------------
__device__ __forceinline__ void attn_local_body(u16* sm, int blk, int tid,
                                                const u16* __restrict__ qkv,
                                                const float* __restrict__ pos1,
                                                u16* __restrict__ attn) {
  u16* pm = sm;            // [4][64][40] = 10240 u16 (PV A operand, halves)
  u16* ks = sm;            // [4][64][32] = 8192 u16, aliases pm
  u16* vt = sm + 10240;    // [4][32][72] = 9216 u16
  const int b = blk >> 4, win = blk & 15;
  const int wy = win >> 2, wx = win & 3;
  const int base_s = (b * 32 + wy * 8) * 32 + wx * 8;
  const int h = tid >> 6, lane = tid & 63;
  const int c16 = lane & 15, g = lane >> 4;

  // ---- Q fragments direct to regs (fly under the K/V staging + barrier)
  s8v af[4];
  {
    const ushort4 z4 = {0, 0, 0, 0};
#pragma unroll
    for (int t = 0; t < 4; ++t) {
      const int row = t * 16 + c16;
      const int s = base_s + (row >> 3) * 32 + (row & 7);
      const u16* qrow = qkv + (size_t)s * 672 + h * 28 + g * 8;
      const ushort4 lo = *(const ushort4*)qrow;
      const ushort4 hi = (g < 3) ? *(const ushort4*)(qrow + 4) : z4;
      af[t] = mk8(lo, hi);
    }
  }
  // ---- stage K: 1792 ushort4, idx = h*448 + t*7 + c4 (k segment @ +224)
#pragma unroll
  for (int m = 0; m < 7; ++m) {
    const int idx = m * 256 + tid;
    const int q7 = idx / 7;              // = hh*64 + t (magic-mul)
    const int c4 = idx - q7 * 7;
    const int t = q7 & 63, hh = q7 >> 6;
    const int s = base_s + (t >> 3) * 32 + (t & 7);
    const ushort4 v = *(const ushort4*)(qkv + (size_t)s * 672 + 224 + hh * 28 + c4 * 4);
    *(ushort4*)(ks + (hh * 64 + t) * 32 + c4 * 4) = v;
  }
  // zero K-pad cols 28..31
  {
    const int hh = tid >> 6, t = tid & 63;
    const ushort4 z = {0, 0, 0, 0};
    *(ushort4*)(ks + (hh * 64 + t) * 32 + 28) = z;
  }
  // ---- stage V transposed -> vt[h][d][t]; lane = t, head = wave.
  {
    const int t = tid & 63, wq = tid >> 6;
    const int s = base_s + (t >> 3) * 32 + (t & 7);
    const u16* vrow = qkv + (size_t)s * 672 + 448 + wq * 28;
    u16* vcolbase = vt + (wq * 32) * 72 + t;
#pragma unroll
    for (int c4 = 0; c4 < 7; ++c4) {
      const ushort4 v = *(const ushort4*)(vrow + c4 * 4);
      u16* col = vcolbase + (c4 * 4) * 72;
      col[0] = v.x; col[72] = v.y; col[144] = v.z; col[216] = v.w;
    }
  }
  __syncthreads();

  s8v bf[4];
  for (int t = 0; t < 4; ++t)
    bf[t] = *(const s8v*)&ks[(h * 64 + t * 16 + c16) * 32 + g * 8];
  const f4v fz = {0.f, 0.f, 0.f, 0.f};
  f4v sc[4][4];
  for (int i = 0; i < 4; ++i)
    for (int j = 0; j < 4; ++j)
      sc[i][j] = MFMA16(af[i], bf[j], fz);
  float lrow[4][4];
  const float* ph = pos1 + h * 4096;
  for (int i = 0; i < 4; ++i) {
    for (int r = 0; r < 4; ++r) {
      const int irow = i * 16 + g * 4 + r;
      float mx = -1e30f;
      for (int j = 0; j < 4; ++j) {
        const float v = sc[i][j][r] * SCALE + ph[irow * 64 + j * 16 + c16];
        sc[i][j][r] = v;
        mx = fmaxf(mx, v);
      }
      for (int d = 1; d < 16; d <<= 1) mx = fmaxf(mx, __shfl_xor(mx, d, 64));
      float sum = 0.f;
      for (int j = 0; j < 4; ++j) {
        const float e = __expf(sc[i][j][r] - mx);
        sc[i][j][r] = e;
        sum += e;
      }
      for (int d = 1; d < 16; d <<= 1) sum += __shfl_xor(sum, d, 64);
      lrow[i][r] = sum;
    }
  }
  __syncthreads();   // all waves done reading ks before pm (aliased) written

  // ---- PV in two 32-col passes over the shared pm buffer
  f4v o[4][2] = {};
#pragma unroll
  for (int kk = 0; kk < 2; ++kk) {
    for (int i = 0; i < 4; ++i)
      for (int r = 0; r < 4; ++r) {
        const int irow = i * 16 + g * 4 + r;
        pm[(h * 64 + irow) * 40 + c16]      = f2bf(sc[i][kk * 2][r]);
        pm[(h * 64 + irow) * 40 + 16 + c16] = f2bf(sc[i][kk * 2 + 1][r]);
      }
    __syncthreads();   // pm half visible
    s8v ap[4], bv[2];
    for (int t = 0; t < 4; ++t)
      ap[t] = *(const s8v*)&pm[(h * 64 + t * 16 + c16) * 40 + g * 8];
    for (int t = 0; t < 2; ++t)
      bv[t] = *(const s8v*)&vt[(h * 32 + t * 16 + c16) * 72 + kk * 32 + g * 8];
    for (int i = 0; i < 4; ++i)
      for (int j = 0; j < 2; ++j)
        o[i][j] = MFMA16(ap[i], bv[j], o[i][j]);
    if (kk == 0) __syncthreads();   // pm half reads done before overwrite
  }
  for (int i = 0; i < 4; ++i)
    for (int r = 0; r < 4; ++r) {
      const int irow = i * 16 + g * 4 + r;
      const int s = base_s + (irow >> 3) * 32 + (irow & 7);
      const float inv = 1.f / lrow[i][r];
      for (int j = 0; j < 2; ++j) {
        const int d = j * 16 + c16;
        if (d < 28)
          attn[(size_t)s * 224 + h * 28 + d] = f2bf(o[i][j][r] * inv);
      }
    }
}

// ---------------------------------------------------------------------------
// Branch 2 body v3: cross-window attention; Q direct-to-reg (no qs), K/V/P
// in LDS: ks 8192 + vt 8224 + p2 2048 = 18464 u16 = 36928 B.
// ---------------------------------------------------------------------------
__device__ __forceinline__ void attn_global_body(u16* smg, int blk, int tid,
                                                 const u16* __restrict__ qkv,
                                                 const float* __restrict__ pos2,
                                                 u16* __restrict__ attn) {
  u16* ks = smg;            // [4][4][16][32] = 8192 u16
  u16* vt = smg + 8192;     // [4] w-stride 2056
  u16* p2 = smg + 16416;    // [4][16][32] = 2048 u16
  const int b = blk >> 4, ig = blk & 15;
  // ---- stage K: 1792 ushort4, idx = (w*16+j)*28 + hq*7 + d4 (seg 1 @ +336)
#pragma unroll
  for (int m = 0; m < 7; ++m) {
    const int idx = m * 256 + tid;
    const int q7 = idx / 7;              // = (w*16+j)*4 + hq
    const int d4 = idx - q7 * 7;
    const int hq = q7 & 3, row = q7 >> 2;
    const int w = row >> 4, j = row & 15;
    const int ii = ig * 4 + w;
    const int y = ii >> 3, x = ii & 7;
    const int s = (b * 32 + (j >> 2) * 8 + y) * 32 + (j & 3) * 8 + x;
    const ushort4 v =
        *(const ushort4*)(qkv + (size_t)s * 672 + 336 + hq * 28 + d4 * 4);
    *(ushort4*)(ks + ((w * 4 + hq) * 16 + j) * 32 + d4 * 4) = v;
  }
  // ---- stage V transposed: lane=(w,j), loop c4
  {
    const int j = tid & 15, w = (tid >> 4) & 3, wq = tid >> 6;
    const int ii = ig * 4 + w;
    const int y = ii >> 3, x = ii & 7;
    const int s = (b * 32 + (j >> 2) * 8 + y) * 32 + (j & 3) * 8 + x;
    const u16* vrow = qkv + (size_t)s * 672 + 560;
    u16* vbase = vt + w * 2056 + j;
#pragma unroll
    for (int c4o = 0; c4o < 7; ++c4o) {
      const int c4 = c4o * 4 + wq;       // 0..27
      const int hq = c4 / 7;             // magic-mul
      const int d4 = c4 - hq * 7;
      const ushort4 v = *(const ushort4*)(vrow + c4 * 4);
      u16* col = vbase + (hq * 32 + d4 * 4) * 16;
      col[0] = v.x; col[16] = v.y; col[32] = v.z; col[48] = v.w;
    }
  }
  // zero K-pad cols 28..31 and vt rows 28..31
  {
    const ushort4 z = {0, 0, 0, 0};
    *(ushort4*)(ks + tid * 32 + 28) = z;
    const int w = tid >> 6, hq = (tid >> 4) & 3;
    const int dd = 28 + ((tid >> 2) & 3), j4 = tid & 3;
    *(ushort4*)(vt + w * 2056 + (hq * 32 + dd) * 16 + j4 * 4) = z;
  }
  __syncthreads();
  const int w = tid >> 6, lane = tid & 63;
  const int c16 = lane & 15, g = lane >> 4;
  const int i = ig * 4 + w;
  const int y = i >> 3, x = i & 7;
  const int w4 = w * 4;
  // spatial row of window c16 at this position (for Q direct loads)
  const int sc16 = (b * 32 + (c16 >> 2) * 8 + y) * 32 + (c16 & 3) * 8 + x;
  const u16* rowp = qkv + (size_t)sc16 * 672;
  const f4v fz = {0.f, 0.f, 0.f, 0.f};
  const ushort4 z4 = {0, 0, 0, 0};
  for (int h = 0; h < 4; ++h) {
    const int qo = 112 + h * 28;
    const ushort4 qlo = *(const ushort4*)(rowp + qo + g * 8);
    const ushort4 qhi = (g < 3) ? *(const ushort4*)(rowp + qo + g * 8 + 4) : z4;
    const s8v aq = mk8(qlo, qhi);
    const s8v bk = *(const s8v*)&ks[((w4 + h) * 16 + c16) * 32 + g * 8];
    const f4v s = MFMA16(aq, bk, fz);
    const float* ph = pos2 + h * 256;
    float l[4];
    for (int r = 0; r < 4; ++r) {
      const float v = s[r] * SCALE + ph[(g * 4 + r) * 16 + c16];
      float mx = v;
      for (int d = 1; d < 16; d <<= 1) mx = fmaxf(mx, __shfl_xor(mx, d, 64));
      const float e = __expf(v - mx);
      float sum = e;
      for (int d = 1; d < 16; d <<= 1) sum += __shfl_xor(sum, d, 64);
      l[r] = sum;
      p2[(w * 16 + g * 4 + r) * 32 + c16] = f2bf(e);
      p2[(w * 16 + g * 4 + r) * 32 + c16 + 16] = 0;   // K pad
    }
    const s8v ap = *(const s8v*)&p2[(w * 16 + c16) * 32 + g * 8];  // same-wave RAW
    f4v o[2];
    for (int nt = 0; nt < 2; ++nt) {
      s8v bv = {0, 0, 0, 0, 0, 0, 0, 0};
      if (g < 2)
        bv = *(const s8v*)&vt[w * 2056 + (h * 32 + nt * 16 + c16) * 16 + g * 8];
      o[nt] = MFMA16(ap, bv, fz);
    }
    for (int nt = 0; nt < 2; ++nt)
      for (int r = 0; r < 4; ++r) {
        const int d = nt * 16 + c16;
        if (d < 28) {
          const int wi = g * 4 + r;
          const int sw = (b * 32 + (wi >> 2) * 8 + y) * 32 + (wi & 3) * 8 + x;
          attn[(size_t)sw * 224 + 112 + h * 28 + d] = f2bf(o[nt][r] / l[r]);
        }
      }
  }
}

// ---------------------------------------------------------------------------
// Fused attention: blocks 0..2047 = local, 2048..4095 = cross-window.
// LDS = 38912 B -> 4 blocks/CU (was 55296 -> 2). Occupancy is the lever.
// ---------------------------------------------------------------------------
__global__ __launch_bounds__(256) void attn_fused(const u16* __restrict__ qkv,
                                                  const float* __restrict__ pos1,
                                                  const float* __restrict__ pos2,
                                                  u16* __restrict__ attn) {
  extern __shared__ u16 sm[];
  const int blk = blockIdx.x;
  const int tid = threadIdx.x;
  if (blk < 2048)
    attn_local_body(sm, blk, tid, qkv, pos1, attn);
  else
    attn_global_body(sm, blk - 2048, tid, qkv, pos2, attn);
}

// ---------------------------------------------------------------------------
// ws layout (bytes):
//   qkv   @ 0          : 131072*672*2 = 176,160,768
//   attn  @ 176160768  : 131072*224*2 =  58,720,256
//   wqkvt @ 234881024  : 768*224*2    =     344,064
//   woutt @ 235225088  : 256*224*2    =     114,688
// ---------------------------------------------------------------------------
extern "C" void kernel_launch(void* const* d_in, const int* in_sizes, int n_in,
                              void* d_out, int out_size, void* d_ws, size_t ws_size,
                              hipStream_t stream) {
  const float* x    = (const float*)d_in[0];
  const float* Wq   = (const float*)d_in[1];
  const float* Wkv  = (const float*)d_in[2];
  const float* Wout = (const float*)d_in[3];
  const float* bout = (const float*)d_in[4];
  const float* pos1 = (const float*)d_in[5];
  const float* pos2 = (const float*)d_in[6];
  char* ws = (char*)d_ws;
  u16* qkv   = (u16*)ws;
  u16* attn  = (u16*)(ws + 176160768);
  u16* wqkvt = (u16*)(ws + 234881024);
  u16* woutt = (u16*)(ws + 235225088);

  prep_kernel<<<dim3(128), 256, 0, stream>>>(Wq, Wkv, Wout, wqkvt, woutt);

  // qkv = x @ [Wq|Wkv]  (A = x f32, cast fused into LDS staging; N=672)
  gemm_af<1, 0, 6><<<dim3(1024), 256, 73728, stream>>>(x, wqkvt, qkv, nullptr, 672, 672);

  attn_fused<<<dim3(4096), 256, 38912, stream>>>(qkv, pos1, pos2, attn);

  // out = attn @ Wout + bout (A = attn bf16; f32 out, N=224 -> 2 n-tiles)
  gemm_af<0, 1, 2><<<dim3(1024), 256, 73728, stream>>>(attn, woutt, d_out, bout, 224, 224);
}

// Round 9
// 368.808 us; speedup vs baseline: 1.1351x; 1.0716x over previous
//
#include <hip/hip_runtime.h>
#include <stdint.h>

typedef short s8v __attribute__((ext_vector_type(8)));
typedef float f4v __attribute__((ext_vector_type(4)));
typedef unsigned short u16;

#define MFMA16(a, b, c) __builtin_amdgcn_mfma_f32_16x16x32_bf16(a, b, c, 0, 0, 0)
#define SCALE 0.1889822365046136f

__device__ __forceinline__ u16 f2bf(float f) {
  union { float f; uint32_t u; } v;
  v.f = f;
  uint32_t u = v.u;
  u += 0x7fffu + ((u >> 16) & 1u);   // RNE
  return (u16)(u >> 16);
}

__device__ __forceinline__ void gld_lds16(const void* g, void* l) {
  __builtin_amdgcn_global_load_lds(
      (const __attribute__((address_space(1))) void*)g,
      (__attribute__((address_space(3))) void*)l, 16, 0, 0);
}

// ---------------------------------------------------------------------------
// prep (R3 version): x f32 -> bf16 streaming cast; pack W^T for QKV (768x224,
// zero-padded rows) and Wout (256x224) as bf16 [n][k].
// ---------------------------------------------------------------------------
__global__ void prep_kernel(const float4* __restrict__ x4,
                            const float* __restrict__ Wq,
                            const float* __restrict__ Wkv,
                            const float* __restrict__ Wout,
                            u16* __restrict__ xb,
                            u16* __restrict__ wqkvt,
                            u16* __restrict__ woutt) {
  const int gsz = gridDim.x * blockDim.x;
  const int gt = blockIdx.x * blockDim.x + threadIdx.x;
  for (int i = gt; i < 7340032; i += gsz) {   // 29360128/4
    float4 v = x4[i];
    ushort4 o;
    o.x = f2bf(v.x); o.y = f2bf(v.y); o.z = f2bf(v.z); o.w = f2bf(v.w);
    ((ushort4*)xb)[i] = o;
  }
  for (int i = gt; i < 768 * 224; i += gsz) {
    const int n = i / 224, k = i - n * 224;
    float v = 0.f;
    if (n < 224) v = Wq[k * 224 + n];
    else if (n < 672) v = Wkv[k * 448 + (n - 224)];
    wqkvt[i] = f2bf(v);
  }
  for (int i = gt; i < 256 * 224; i += gsz) {
    const int n = i / 224, k = i - n * 224;
    const float v = (n < 224) ? Wout[k * 224 + n] : 0.f;
    woutt[i] = f2bf(v);
  }
}

// ---------------------------------------------------------------------------
// gemm_af (for the output GEMM only): C = A[M][224] * Bt^T, A bf16 via
// gld_lds persistent 128x224 tile, B [128][32] dbuf distance-2. Unchanged.
// ---------------------------------------------------------------------------
template <int OUT_F32, int NTILES>
__global__ __launch_bounds__(256) void gemm_af(const u16* __restrict__ Ap,
                                               const u16* __restrict__ Bt,
                                               void* __restrict__ Cp,
                                               const float* __restrict__ bias,
                                               int Nvalid, int ldc) {
  extern __shared__ u16 smem[];
  u16* As  = smem;            // [128][224] = 57344 B
  u16* Bs0 = smem + 28672;
  u16* Bs1 = smem + 32768;
  const int tid = threadIdx.x;
  const int wave = tid >> 6, lane = tid & 63;
  const int c16 = lane & 15, g = lane >> 4;
  const int m0 = blockIdx.x * 128;
  const int wm = wave & 1, wn = wave >> 1;

  const int fbw = wave * 1024 + lane * 16;
  const int brow0 = fbw >> 6, bcol0 = (fbw & 63) >> 1;

#define STAGE_B(ntile, ktile, bufp)                                            \
  do {                                                                         \
    char* bb = (char*)((bufp) ? Bs1 : Bs0) + wave * 1024;                      \
    const u16* src =                                                           \
        Bt + (size_t)((ntile) * 128 + brow0) * 224 + (ktile) * 32 + bcol0;     \
    gld_lds16(src, bb);                                                        \
    gld_lds16(src + (size_t)64 * 224, bb + 4096);                              \
  } while (0)

  STAGE_B(0, 0, 0);
  if (NTILES * 7 > 1) STAGE_B(0, 1, 1);

  for (int rnd = 0; rnd < 14; ++rnd) {
    const int fb = rnd * 4096 + fbw;
    const int row = fb / 448;
    const int off = fb - row * 448;
    gld_lds16(Ap + (size_t)(m0 + row) * 224 + (off >> 1),
              (char*)As + rnd * 4096 + wave * 1024);
  }
  __syncthreads();

  for (int nt = 0; nt < NTILES; ++nt) {
    f4v acc[4][4] = {};
    for (int kt = 0; kt < 7; ++kt) {
      const int t = nt * 7 + kt;
      const u16* Bs = (t & 1) ? Bs1 : Bs0;
      s8v af[4], bf[4];
      for (int tt = 0; tt < 4; ++tt)
        af[tt] = *(const s8v*)&As[(wm * 64 + tt * 16 + c16) * 224 + kt * 32 + g * 8];
      for (int tt = 0; tt < 4; ++tt)
        bf[tt] = *(const s8v*)&Bs[(wn * 64 + tt * 16 + c16) * 32 + g * 8];
      for (int i = 0; i < 4; ++i)
        for (int j = 0; j < 4; ++j)
          acc[i][j] = MFMA16(af[i], bf[j], acc[i][j]);
      __syncthreads();
      const int ns = t + 2;
      if (ns < NTILES * 7) {
        const int nnt = ns / 7;
        STAGE_B(nnt, ns - nnt * 7, t & 1);
      }
    }
    const int n0 = nt * 128;
    for (int i = 0; i < 4; ++i) {
      const int rowb = m0 + wm * 64 + i * 16 + g * 4;
      for (int j = 0; j < 4; ++j) {
        const int col = n0 + wn * 64 + j * 16 + c16;
        if (col < Nvalid) {
          if (OUT_F32) {
            const float bz = bias[col];
            for (int r = 0; r < 4; ++r)
              ((float*)Cp)[(size_t)(rowb + r) * ldc + col] = acc[i][j][r] + bz;
          } else {
            for (int r = 0; r < 4; ++r)
              ((u16*)Cp)[(size_t)(rowb + r) * ldc + col] = f2bf(acc[i][j][r]);
          }
        }
      }
    }
  }
#undef STAGE_B
}

// ---------------------------------------------------------------------------
// FUSED qkv-GEMM + attention. Blocks 0..2047 local, 2048..4095 cross-window.
// Phase 1 (mini-GEMM): A = 64 x-rows (window rows / gathered rows) staged
//   bf16 via gld_lds [64][224]; B = the branch's 336 W^T rows streamed as
//   [336][32] k-subtiles (dbuf, distance-2, 1 barrier/step, 7 steps).
//   Wave w owns col-tiles {w,4+w,...} x all 4 row-strips (B-frag reused 4x).
//   C is written STRAIGHT into the attn LDS layouts as f2bf(acc) — the bf16
//   values are bit-identical to the old memory-materialized qkv, so the
//   attn math (and absmax) is unchanged. Kills gemm1 + 360MB of HBM traffic.
// Phase 2: exact R6 attn bodies (best measured).
// LDS: phase1 As 14336 + Bs0 10752 + Bs1 10752 = 35840 u16 = 71680 B;
// phase2 local qs@0/ks@8192/vt@18432/pm@0(alias) = 27648 u16;
// phase2 global qs/ks/vtG@16384(w-stride 2056)/p2@24608 = 26656 u16.
// Peak 71680 B -> 2 blocks/CU. VGPR target <256 via launch_bounds(256,2).
// ---------------------------------------------------------------------------
__global__ __launch_bounds__(256, 2) void attn_fused(
    const u16* __restrict__ xb, const u16* __restrict__ Wt,
    const float* __restrict__ pos1, const float* __restrict__ pos2,
    u16* __restrict__ attn) {
  extern __shared__ u16 sm[];
  u16* As  = sm;            // [64][224] = 14336 u16
  u16* Bs0 = sm + 14336;    // [336][32] = 10752 u16
  u16* Bs1 = sm + 25088;    // ends 35840 u16
  const int blk0 = blockIdx.x;
  const int local = (blk0 < 2048) ? 1 : 0;
  const int blk = local ? blk0 : blk0 - 2048;
  const int tid = threadIdx.x;
  const int wave = tid >> 6, lane = tid & 63;
  const int c16 = lane & 15, g = lane >> 4;
  const int b = blk >> 4, sub = blk & 15;

  int base_s = 0, ig = 0;
  if (local) {
    base_s = (b * 32 + (sub >> 2) * 8) * 32 + (sub & 3) * 8;
  } else {
    ig = sub;
  }

  // ---- stage A: 64 rows x 28 chunks(16B) = 7 rounds; dst linear = chunk*16
#pragma unroll
  for (int m = 0; m < 7; ++m) {
    const int chunk = m * 256 + tid;
    const int row = chunk / 28;          // magic-mul
    const int c = chunk - row * 28;
    int s;
    if (local) {
      s = base_s + (row >> 3) * 32 + (row & 7);
    } else {
      const int w2 = row >> 4, j = row & 15;
      const int ii = ig * 4 + w2;
      const int y = ii >> 3, x = ii & 7;
      s = (b * 32 + (j >> 2) * 8 + y) * 32 + (j & 3) * 8 + x;
    }
    gld_lds16(xb + (size_t)s * 224 + c * 8, (char*)As + chunk * 16);
  }

  const int qoff = local ? 0 : 112;
  // B rows 0..335 -> W^T rows {qoff..+111, 224+qoff.., 448+qoff..}
#define STAGE_W(ktile, buf)                                                   \
  do {                                                                        \
    for (int mm = 0; mm < 6; ++mm) {                                          \
      const int ch = mm * 256 + tid;                                          \
      if (ch < 1344) {                                                        \
        const int brow = ch >> 2, bc = (ch & 3) * 8;                          \
        const int n = qoff + brow + ((brow >= 112) ? 112 : 0) +               \
                      ((brow >= 224) ? 112 : 0);                              \
        gld_lds16(Wt + (size_t)n * 224 + (ktile) * 32 + bc,                   \
                  (char*)(buf) + ch * 16);                                    \
      }                                                                       \
    }                                                                         \
  } while (0)

  STAGE_W(0, Bs0);
  STAGE_W(1, Bs1);
  __syncthreads();

  // ---- mini-GEMM: acc[tile j][strip], tile = j*4+wave (<21), K = 7 steps
  f4v acc[6][4] = {};
  for (int kt = 0; kt < 7; ++kt) {
    const u16* Bs = (kt & 1) ? Bs1 : Bs0;
    s8v af[4];
#pragma unroll
    for (int st = 0; st < 4; ++st)
      af[st] = *(const s8v*)&As[(st * 16 + c16) * 224 + kt * 32 + g * 8];
#pragma unroll
    for (int j = 0; j < 6; ++j) {
      const int tile = j * 4 + wave;
      if (tile < 21) {
        const s8v bf = *(const s8v*)&Bs[(tile * 16 + c16) * 32 + g * 8];
#pragma unroll
        for (int st = 0; st < 4; ++st)
          acc[j][st] = MFMA16(af[st], bf, acc[j][st]);
      }
    }
    __syncthreads();       // stage(kt+1) covered; buffer free; As/Bs reads done
    if (kt + 2 < 7) STAGE_W(kt + 2, (kt & 1) ? Bs1 : Bs0);
  }

  // ---- phase-2 LDS views (overlap As/Bs: dead after the kt=6 barrier)
  u16* qs  = sm;            // [256][32] = 8192 u16 (local: [h*64+t]; global: [(w*4+h)*16+j])
  u16* ks  = sm + 8192;     // [256][32]
  u16* vtL = sm + 18432;    // [4][32][72] = 9216 u16
  u16* vtG = sm + 16384;    // [4] w-stride 2056 = 8224 u16
  u16* pm  = sm;            // local P, [4][64][72] = 18432 u16 (alias qs+ks)
  u16* p2  = sm + 24608;    // global P, [4][16][32] = 2048 u16

  // ---- C -> LDS in attn layouts; values bit-identical to old qkv
#pragma unroll
  for (int j = 0; j < 6; ++j) {
    const int tile = j * 4 + wave;
    if (tile < 21) {
      const int seg = (tile >= 14) ? 2 : ((tile >= 7) ? 1 : 0);
      const int nn = tile * 16 + c16 - seg * 112;   // 0..111
      const int h = ((nn >= 28) ? 1 : 0) + ((nn >= 56) ? 1 : 0) + ((nn >= 84) ? 1 : 0);
      const int d = nn - h * 28;
#pragma unroll
      for (int st = 0; st < 4; ++st) {
        if (seg == 2) {      // V: 4 consecutive tokens -> one 8B store
          ushort4 o;
          o.x = f2bf(acc[j][st][0]); o.y = f2bf(acc[j][st][1]);
          o.z = f2bf(acc[j][st][2]); o.w = f2bf(acc[j][st][3]);
          if (local)
            *(ushort4*)&vtL[(h * 32 + d) * 72 + st * 16 + g * 4] = o;
          else
            *(ushort4*)&vtG[st * 2056 + (h * 32 + d) * 16 + g * 4] = o;
        } else {
          u16* dst = seg ? ks : qs;
#pragma unroll
          for (int r = 0; r < 4; ++r) {
            const u16 v = f2bf(acc[j][st][r]);
            if (local)
              dst[(h * 64 + st * 16 + g * 4 + r) * 32 + d] = v;
            else
              dst[((st * 4 + h) * 16 + g * 4 + r) * 32 + d] = v;
          }
        }
      }
    }
  }
  // zero K-pads d=28..31 of qs/ks (all 256 rows); global: vtG rows 28..31
  {
    const ushort4 z = {0, 0, 0, 0};
    *(ushort4*)(qs + tid * 32 + 28) = z;
    *(ushort4*)(ks + tid * 32 + 28) = z;
    if (!local) {
      const int w2 = tid >> 6, hq = (tid >> 4) & 3;
      const int dd = 28 + ((tid >> 2) & 3), j4 = tid & 3;
      *(ushort4*)(vtG + w2 * 2056 + (hq * 32 + dd) * 16 + j4 * 4) = z;
    }
  }
  __syncthreads();

  const f4v fz = {0.f, 0.f, 0.f, 0.f};
  if (local) {
    // ================= R6 local attn body =================
    const int h = wave;
    s8v af2[4], bf2[4];
    for (int t = 0; t < 4; ++t)
      af2[t] = *(const s8v*)&qs[(h * 64 + t * 16 + c16) * 32 + g * 8];
    for (int t = 0; t < 4; ++t)
      bf2[t] = *(const s8v*)&ks[(h * 64 + t * 16 + c16) * 32 + g * 8];
    f4v sc[4][4];
    for (int i = 0; i < 4; ++i)
      for (int j = 0; j < 4; ++j)
        sc[i][j] = MFMA16(af2[i], bf2[j], fz);
    float lrow[4][4];
    const float* ph = pos1 + h * 4096;
    for (int i = 0; i < 4; ++i) {
      for (int r = 0; r < 4; ++r) {
        const int irow = i * 16 + g * 4 + r;
        float mx = -1e30f;
        for (int j = 0; j < 4; ++j) {
          const float v = sc[i][j][r] * SCALE + ph[irow * 64 + j * 16 + c16];
          sc[i][j][r] = v;
          mx = fmaxf(mx, v);
        }
        for (int dd = 1; dd < 16; dd <<= 1) mx = fmaxf(mx, __shfl_xor(mx, dd, 64));
        float sum = 0.f;
        for (int j = 0; j < 4; ++j) {
          const float e = __expf(sc[i][j][r] - mx);
          sc[i][j][r] = e;
          sum += e;
        }
        for (int dd = 1; dd < 16; dd <<= 1) sum += __shfl_xor(sum, dd, 64);
        lrow[i][r] = sum;
      }
    }
    __syncthreads();   // qs/ks frag reads done before pm (aliased) written
    for (int i = 0; i < 4; ++i)
      for (int r = 0; r < 4; ++r) {
        const int irow = i * 16 + g * 4 + r;
        for (int j = 0; j < 4; ++j)
          pm[(h * 64 + irow) * 72 + j * 16 + c16] = f2bf(sc[i][j][r]);
      }
    f4v o[4][2] = {};
    for (int kk = 0; kk < 2; ++kk) {
      s8v ap[4], bv[2];
      for (int t = 0; t < 4; ++t)
        ap[t] = *(const s8v*)&pm[(h * 64 + t * 16 + c16) * 72 + kk * 32 + g * 8];
      for (int t = 0; t < 2; ++t)
        bv[t] = *(const s8v*)&vtL[(h * 32 + t * 16 + c16) * 72 + kk * 32 + g * 8];
      for (int i = 0; i < 4; ++i)
        for (int j = 0; j < 2; ++j)
          o[i][j] = MFMA16(ap[i], bv[j], o[i][j]);
    }
    for (int i = 0; i < 4; ++i)
      for (int r = 0; r < 4; ++r) {
        const int irow = i * 16 + g * 4 + r;
        const int s = base_s + (irow >> 3) * 32 + (irow & 7);
        const float inv = 1.f / lrow[i][r];
        for (int j = 0; j < 2; ++j) {
          const int d = j * 16 + c16;
          if (d < 28)
            attn[(size_t)s * 224 + h * 28 + d] = f2bf(o[i][j][r] * inv);
        }
      }
  } else {
    // ================= R6 global attn body =================
    const int w = wave;
    const int i = ig * 4 + w;
    const int y = i >> 3, x = i & 7;
    const int w4 = w * 4;
    for (int h = 0; h < 4; ++h) {
      const s8v aq = *(const s8v*)&qs[((w4 + h) * 16 + c16) * 32 + g * 8];
      const s8v bk = *(const s8v*)&ks[((w4 + h) * 16 + c16) * 32 + g * 8];
      const f4v s = MFMA16(aq, bk, fz);
      const float* ph = pos2 + h * 256;
      float l[4];
      for (int r = 0; r < 4; ++r) {
        const float v = s[r] * SCALE + ph[(g * 4 + r) * 16 + c16];
        float mx = v;
        for (int dd = 1; dd < 16; dd <<= 1) mx = fmaxf(mx, __shfl_xor(mx, dd, 64));
        const float e = __expf(v - mx);
        float sum = e;
        for (int dd = 1; dd < 16; dd <<= 1) sum += __shfl_xor(sum, dd, 64);
        l[r] = sum;
        p2[(w * 16 + g * 4 + r) * 32 + c16] = f2bf(e);
        p2[(w * 16 + g * 4 + r) * 32 + c16 + 16] = 0;   // K pad
      }
      const s8v ap = *(const s8v*)&p2[(w * 16 + c16) * 32 + g * 8];  // same-wave RAW
      f4v o[2];
      for (int nt = 0; nt < 2; ++nt) {
        s8v bv = {0, 0, 0, 0, 0, 0, 0, 0};
        if (g < 2)
          bv = *(const s8v*)&vtG[w * 2056 + (h * 32 + nt * 16 + c16) * 16 + g * 8];
        o[nt] = MFMA16(ap, bv, fz);
      }
      for (int nt = 0; nt < 2; ++nt)
        for (int r = 0; r < 4; ++r) {
          const int d = nt * 16 + c16;
          if (d < 28) {
            const int wi = g * 4 + r;
            const int sw = (b * 32 + (wi >> 2) * 8 + y) * 32 + (wi & 3) * 8 + x;
            attn[(size_t)sw * 224 + 112 + h * 28 + d] = f2bf(o[nt][r] / l[r]);
          }
        }
    }
  }
#undef STAGE_W
}

// ---------------------------------------------------------------------------
// ws layout (bytes):
//   xb    @ 0          : 131072*224*2 = 58,720,256
//   attn  @ 58720256   : 131072*224*2 = 58,720,256
//   wqkvt @ 117440512  : 768*224*2    =    344,064
//   woutt @ 117784576  : 256*224*2    =    114,688
// (qkv is never materialized anymore)
// ---------------------------------------------------------------------------
extern "C" void kernel_launch(void* const* d_in, const int* in_sizes, int n_in,
                              void* d_out, int out_size, void* d_ws, size_t ws_size,
                              hipStream_t stream) {
  const float* x    = (const float*)d_in[0];
  const float* Wq   = (const float*)d_in[1];
  const float* Wkv  = (const float*)d_in[2];
  const float* Wout = (const float*)d_in[3];
  const float* bout = (const float*)d_in[4];
  const float* pos1 = (const float*)d_in[5];
  const float* pos2 = (const float*)d_in[6];
  char* ws = (char*)d_ws;
  u16* xb    = (u16*)ws;
  u16* attn  = (u16*)(ws + 58720256);
  u16* wqkvt = (u16*)(ws + 117440512);
  u16* woutt = (u16*)(ws + 117784576);

  prep_kernel<<<dim3(1024), 256, 0, stream>>>(
      (const float4*)x, Wq, Wkv, Wout, xb, wqkvt, woutt);

  // fused qkv-GEMM + attention (no qkv materialization)
  attn_fused<<<dim3(4096), 256, 71680, stream>>>(xb, wqkvt, pos1, pos2, attn);

  // out = attn @ Wout + bout (f32 out, N=224 -> 2 n-tiles)
  gemm_af<1, 2><<<dim3(1024), 256, 73728, stream>>>(attn, woutt, d_out, bout, 224, 224);
}

// Round 10
// 365.860 us; speedup vs baseline: 1.1442x; 1.0081x over previous
//
#include <hip/hip_runtime.h>
#include <stdint.h>

typedef short s8v __attribute__((ext_vector_type(8)));
typedef float f4v __attribute__((ext_vector_type(4)));
typedef unsigned short u16;

#define MFMA16(a, b, c) __builtin_amdgcn_mfma_f32_16x16x32_bf16(a, b, c, 0, 0, 0)
#define SCALE 0.1889822365046136f

__device__ __forceinline__ u16 f2bf(float f) {
  union { float f; uint32_t u; } v;
  v.f = f;
  uint32_t u = v.u;
  u += 0x7fffu + ((u >> 16) & 1u);   // RNE
  return (u16)(u >> 16);
}

__device__ __forceinline__ void gld_lds16(const void* g, void* l) {
  __builtin_amdgcn_global_load_lds(
      (const __attribute__((address_space(1))) void*)g,
      (__attribute__((address_space(3))) void*)l, 16, 0, 0);
}

// ---------------------------------------------------------------------------
// prep: x f32 -> bf16 streaming cast; pack W^T for QKV (768x224, zero-padded
// rows) and Wout (256x224) as bf16 [n][k].
// ---------------------------------------------------------------------------
__global__ void prep_kernel(const float4* __restrict__ x4,
                            const float* __restrict__ Wq,
                            const float* __restrict__ Wkv,
                            const float* __restrict__ Wout,
                            u16* __restrict__ xb,
                            u16* __restrict__ wqkvt,
                            u16* __restrict__ woutt) {
  const int gsz = gridDim.x * blockDim.x;
  const int gt = blockIdx.x * blockDim.x + threadIdx.x;
  for (int i = gt; i < 7340032; i += gsz) {   // 29360128/4
    float4 v = x4[i];
    ushort4 o;
    o.x = f2bf(v.x); o.y = f2bf(v.y); o.z = f2bf(v.z); o.w = f2bf(v.w);
    ((ushort4*)xb)[i] = o;
  }
  for (int i = gt; i < 768 * 224; i += gsz) {
    const int n = i / 224, k = i - n * 224;
    float v = 0.f;
    if (n < 224) v = Wq[k * 224 + n];
    else if (n < 672) v = Wkv[k * 448 + (n - 224)];
    wqkvt[i] = f2bf(v);
  }
  for (int i = gt; i < 256 * 224; i += gsz) {
    const int n = i / 224, k = i - n * 224;
    const float v = (n < 224) ? Wout[k * 224 + n] : 0.f;
    woutt[i] = f2bf(v);
  }
}

// ---------------------------------------------------------------------------
// gemm_af (output GEMM only): C = A[M][224] * Bt^T. Unchanged.
// ---------------------------------------------------------------------------
template <int OUT_F32, int NTILES>
__global__ __launch_bounds__(256) void gemm_af(const u16* __restrict__ Ap,
                                               const u16* __restrict__ Bt,
                                               void* __restrict__ Cp,
                                               const float* __restrict__ bias,
                                               int Nvalid, int ldc) {
  extern __shared__ u16 smem[];
  u16* As  = smem;            // [128][224] = 57344 B
  u16* Bs0 = smem + 28672;
  u16* Bs1 = smem + 32768;
  const int tid = threadIdx.x;
  const int wave = tid >> 6, lane = tid & 63;
  const int c16 = lane & 15, g = lane >> 4;
  const int m0 = blockIdx.x * 128;
  const int wm = wave & 1, wn = wave >> 1;

  const int fbw = wave * 1024 + lane * 16;
  const int brow0 = fbw >> 6, bcol0 = (fbw & 63) >> 1;

#define STAGE_B(ntile, ktile, bufp)                                            \
  do {                                                                         \
    char* bb = (char*)((bufp) ? Bs1 : Bs0) + wave * 1024;                      \
    const u16* src =                                                           \
        Bt + (size_t)((ntile) * 128 + brow0) * 224 + (ktile) * 32 + bcol0;     \
    gld_lds16(src, bb);                                                        \
    gld_lds16(src + (size_t)64 * 224, bb + 4096);                              \
  } while (0)

  STAGE_B(0, 0, 0);
  if (NTILES * 7 > 1) STAGE_B(0, 1, 1);

  for (int rnd = 0; rnd < 14; ++rnd) {
    const int fb = rnd * 4096 + fbw;
    const int row = fb / 448;
    const int off = fb - row * 448;
    gld_lds16(Ap + (size_t)(m0 + row) * 224 + (off >> 1),
              (char*)As + rnd * 4096 + wave * 1024);
  }
  __syncthreads();

  for (int nt = 0; nt < NTILES; ++nt) {
    f4v acc[4][4] = {};
    for (int kt = 0; kt < 7; ++kt) {
      const int t = nt * 7 + kt;
      const u16* Bs = (t & 1) ? Bs1 : Bs0;
      s8v af[4], bf[4];
      for (int tt = 0; tt < 4; ++tt)
        af[tt] = *(const s8v*)&As[(wm * 64 + tt * 16 + c16) * 224 + kt * 32 + g * 8];
      for (int tt = 0; tt < 4; ++tt)
        bf[tt] = *(const s8v*)&Bs[(wn * 64 + tt * 16 + c16) * 32 + g * 8];
      for (int i = 0; i < 4; ++i)
        for (int j = 0; j < 4; ++j)
          acc[i][j] = MFMA16(af[i], bf[j], acc[i][j]);
      __syncthreads();
      const int ns = t + 2;
      if (ns < NTILES * 7) {
        const int nnt = ns / 7;
        STAGE_B(nnt, ns - nnt * 7, t & 1);
      }
    }
    const int n0 = nt * 128;
    for (int i = 0; i < 4; ++i) {
      const int rowb = m0 + wm * 64 + i * 16 + g * 4;
      for (int j = 0; j < 4; ++j) {
        const int col = n0 + wn * 64 + j * 16 + c16;
        if (col < Nvalid) {
          if (OUT_F32) {
            const float bz = bias[col];
            for (int r = 0; r < 4; ++r)
              ((float*)Cp)[(size_t)(rowb + r) * ldc + col] = acc[i][j][r] + bz;
          } else {
            for (int r = 0; r < 4; ++r)
              ((u16*)Cp)[(size_t)(rowb + r) * ldc + col] = f2bf(acc[i][j][r]);
          }
        }
      }
    }
  }
#undef STAGE_B
}

// ---------------------------------------------------------------------------
// FUSED qkv-GEMM + attention (R9 structure; R10 change: qs/ks row stride
// padded 32 -> 40 u16). The phase-1 C->LDS scatter stores at stride 32 had
// bank = (row*16 + d/2)%32 with the g-term collapsing (64g%32=0) -> 8-way
// conflicts on ~224 scalar stores/thread (the 9.55M counter). Stride 40
// (80B, keeps b128 16B-alignment) gives bank = (row*20 + d/2)%32 with
// 16g spread -> 4-way. Pure layout change; values/order identical.
// LDS: phase1 As 14336 + Bs0/Bs1 10752 each = 35840 u16 = 71680 B (peak);
// phase2 local: qs[256][40]@0 + ks[256][40]@10240 + vtL@20480 (9216),
//   pm[4][64][72]=18432 aliases qs+ks;
// phase2 global: qs/ks same + vtG@20480 (8224) + p2@28704 (2048).
// ---------------------------------------------------------------------------
__global__ __launch_bounds__(256, 2) void attn_fused(
    const u16* __restrict__ xb, const u16* __restrict__ Wt,
    const float* __restrict__ pos1, const float* __restrict__ pos2,
    u16* __restrict__ attn) {
  extern __shared__ u16 sm[];
  u16* As  = sm;            // [64][224] = 14336 u16
  u16* Bs0 = sm + 14336;    // [336][32] = 10752 u16
  u16* Bs1 = sm + 25088;    // ends 35840 u16
  const int blk0 = blockIdx.x;
  const int local = (blk0 < 2048) ? 1 : 0;
  const int blk = local ? blk0 : blk0 - 2048;
  const int tid = threadIdx.x;
  const int wave = tid >> 6, lane = tid & 63;
  const int c16 = lane & 15, g = lane >> 4;
  const int b = blk >> 4, sub = blk & 15;

  int base_s = 0, ig = 0;
  if (local) {
    base_s = (b * 32 + (sub >> 2) * 8) * 32 + (sub & 3) * 8;
  } else {
    ig = sub;
  }

  // ---- stage A: 64 rows x 28 chunks(16B) = 7 rounds; dst linear = chunk*16
#pragma unroll
  for (int m = 0; m < 7; ++m) {
    const int chunk = m * 256 + tid;
    const int row = chunk / 28;          // magic-mul
    const int c = chunk - row * 28;
    int s;
    if (local) {
      s = base_s + (row >> 3) * 32 + (row & 7);
    } else {
      const int w2 = row >> 4, j = row & 15;
      const int ii = ig * 4 + w2;
      const int y = ii >> 3, x = ii & 7;
      s = (b * 32 + (j >> 2) * 8 + y) * 32 + (j & 3) * 8 + x;
    }
    gld_lds16(xb + (size_t)s * 224 + c * 8, (char*)As + chunk * 16);
  }

  const int qoff = local ? 0 : 112;
  // B rows 0..335 -> W^T rows {qoff..+111, 224+qoff.., 448+qoff..}
#define STAGE_W(ktile, buf)                                                   \
  do {                                                                        \
    for (int mm = 0; mm < 6; ++mm) {                                          \
      const int ch = mm * 256 + tid;                                          \
      if (ch < 1344) {                                                        \
        const int brow = ch >> 2, bc = (ch & 3) * 8;                          \
        const int n = qoff + brow + ((brow >= 112) ? 112 : 0) +               \
                      ((brow >= 224) ? 112 : 0);                              \
        gld_lds16(Wt + (size_t)n * 224 + (ktile) * 32 + bc,                   \
                  (char*)(buf) + ch * 16);                                    \
      }                                                                       \
    }                                                                         \
  } while (0)

  STAGE_W(0, Bs0);
  STAGE_W(1, Bs1);
  __syncthreads();

  // ---- mini-GEMM: acc[tile j][strip], tile = j*4+wave (<21), K = 7 steps
  f4v acc[6][4] = {};
  for (int kt = 0; kt < 7; ++kt) {
    const u16* Bs = (kt & 1) ? Bs1 : Bs0;
    s8v af[4];
#pragma unroll
    for (int st = 0; st < 4; ++st)
      af[st] = *(const s8v*)&As[(st * 16 + c16) * 224 + kt * 32 + g * 8];
#pragma unroll
    for (int j = 0; j < 6; ++j) {
      const int tile = j * 4 + wave;
      if (tile < 21) {
        const s8v bf = *(const s8v*)&Bs[(tile * 16 + c16) * 32 + g * 8];
#pragma unroll
        for (int st = 0; st < 4; ++st)
          acc[j][st] = MFMA16(af[st], bf, acc[j][st]);
      }
    }
    __syncthreads();       // stage(kt+1) covered; buffer free; As/Bs reads done
    if (kt + 2 < 7) STAGE_W(kt + 2, (kt & 1) ? Bs1 : Bs0);
  }

  // ---- phase-2 LDS views (overlap As/Bs: dead after the final barrier)
  u16* qs  = sm;            // [256][40] = 10240 u16 (padded stride)
  u16* ks  = sm + 10240;    // [256][40]
  u16* vtL = sm + 20480;    // [4][32][72] = 9216 u16
  u16* vtG = sm + 20480;    // [4] w-stride 2056 = 8224 u16
  u16* pm  = sm;            // local P, [4][64][72] = 18432 u16 (alias qs+ks)
  u16* p2  = sm + 28704;    // global P, [4][16][32] = 2048 u16

  // ---- C -> LDS in attn layouts; values bit-identical to old qkv
#pragma unroll
  for (int j = 0; j < 6; ++j) {
    const int tile = j * 4 + wave;
    if (tile < 21) {
      const int seg = (tile >= 14) ? 2 : ((tile >= 7) ? 1 : 0);
      const int nn = tile * 16 + c16 - seg * 112;   // 0..111
      const int h = ((nn >= 28) ? 1 : 0) + ((nn >= 56) ? 1 : 0) + ((nn >= 84) ? 1 : 0);
      const int d = nn - h * 28;
#pragma unroll
      for (int st = 0; st < 4; ++st) {
        if (seg == 2) {      // V: 4 consecutive tokens -> one 8B store
          ushort4 o;
          o.x = f2bf(acc[j][st][0]); o.y = f2bf(acc[j][st][1]);
          o.z = f2bf(acc[j][st][2]); o.w = f2bf(acc[j][st][3]);
          if (local)
            *(ushort4*)&vtL[(h * 32 + d) * 72 + st * 16 + g * 4] = o;
          else
            *(ushort4*)&vtG[st * 2056 + (h * 32 + d) * 16 + g * 4] = o;
        } else {
          u16* dst = seg ? ks : qs;
#pragma unroll
          for (int r = 0; r < 4; ++r) {
            const u16 v = f2bf(acc[j][st][r]);
            if (local)
              dst[(h * 64 + st * 16 + g * 4 + r) * 40 + d] = v;
            else
              dst[((st * 4 + h) * 16 + g * 4 + r) * 40 + d] = v;
          }
        }
      }
    }
  }
  // zero K-pads d=28..31 of qs/ks (all 256 rows); global: vtG rows 28..31
  {
    const ushort4 z = {0, 0, 0, 0};
    *(ushort4*)(qs + tid * 40 + 28) = z;
    *(ushort4*)(ks + tid * 40 + 28) = z;
    if (!local) {
      const int w2 = tid >> 6, hq = (tid >> 4) & 3;
      const int dd = 28 + ((tid >> 2) & 3), j4 = tid & 3;
      *(ushort4*)(vtG + w2 * 2056 + (hq * 32 + dd) * 16 + j4 * 4) = z;
    }
  }
  __syncthreads();

  const f4v fz = {0.f, 0.f, 0.f, 0.f};
  if (local) {
    // ================= local attn body =================
    const int h = wave;
    s8v af2[4], bf2[4];
    for (int t = 0; t < 4; ++t)
      af2[t] = *(const s8v*)&qs[(h * 64 + t * 16 + c16) * 40 + g * 8];
    for (int t = 0; t < 4; ++t)
      bf2[t] = *(const s8v*)&ks[(h * 64 + t * 16 + c16) * 40 + g * 8];
    f4v sc[4][4];
    for (int i = 0; i < 4; ++i)
      for (int j = 0; j < 4; ++j)
        sc[i][j] = MFMA16(af2[i], bf2[j], fz);
    float lrow[4][4];
    const float* ph = pos1 + h * 4096;
    for (int i = 0; i < 4; ++i) {
      for (int r = 0; r < 4; ++r) {
        const int irow = i * 16 + g * 4 + r;
        float mx = -1e30f;
        for (int j = 0; j < 4; ++j) {
          const float v = sc[i][j][r] * SCALE + ph[irow * 64 + j * 16 + c16];
          sc[i][j][r] = v;
          mx = fmaxf(mx, v);
        }
        for (int dd = 1; dd < 16; dd <<= 1) mx = fmaxf(mx, __shfl_xor(mx, dd, 64));
        float sum = 0.f;
        for (int j = 0; j < 4; ++j) {
          const float e = __expf(sc[i][j][r] - mx);
          sc[i][j][r] = e;
          sum += e;
        }
        for (int dd = 1; dd < 16; dd <<= 1) sum += __shfl_xor(sum, dd, 64);
        lrow[i][r] = sum;
      }
    }
    __syncthreads();   // qs/ks frag reads done before pm (aliased) written
    for (int i = 0; i < 4; ++i)
      for (int r = 0; r < 4; ++r) {
        const int irow = i * 16 + g * 4 + r;
        for (int j = 0; j < 4; ++j)
          pm[(h * 64 + irow) * 72 + j * 16 + c16] = f2bf(sc[i][j][r]);
      }
    f4v o[4][2] = {};
    for (int kk = 0; kk < 2; ++kk) {
      s8v ap[4], bv[2];
      for (int t = 0; t < 4; ++t)
        ap[t] = *(const s8v*)&pm[(h * 64 + t * 16 + c16) * 72 + kk * 32 + g * 8];
      for (int t = 0; t < 2; ++t)
        bv[t] = *(const s8v*)&vtL[(h * 32 + t * 16 + c16) * 72 + kk * 32 + g * 8];
      for (int i = 0; i < 4; ++i)
        for (int j = 0; j < 2; ++j)
          o[i][j] = MFMA16(ap[i], bv[j], o[i][j]);
    }
    for (int i = 0; i < 4; ++i)
      for (int r = 0; r < 4; ++r) {
        const int irow = i * 16 + g * 4 + r;
        const int s = base_s + (irow >> 3) * 32 + (irow & 7);
        const float inv = 1.f / lrow[i][r];
        for (int j = 0; j < 2; ++j) {
          const int d = j * 16 + c16;
          if (d < 28)
            attn[(size_t)s * 224 + h * 28 + d] = f2bf(o[i][j][r] * inv);
        }
      }
  } else {
    // ================= global attn body =================
    const int w = wave;
    const int i = ig * 4 + w;
    const int y = i >> 3, x = i & 7;
    const int w4 = w * 4;
    for (int h = 0; h < 4; ++h) {
      const s8v aq = *(const s8v*)&qs[((w4 + h) * 16 + c16) * 40 + g * 8];
      const s8v bk = *(const s8v*)&ks[((w4 + h) * 16 + c16) * 40 + g * 8];
      const f4v s = MFMA16(aq, bk, fz);
      const float* ph = pos2 + h * 256;
      float l[4];
      for (int r = 0; r < 4; ++r) {
        const float v = s[r] * SCALE + ph[(g * 4 + r) * 16 + c16];
        float mx = v;
        for (int dd = 1; dd < 16; dd <<= 1) mx = fmaxf(mx, __shfl_xor(mx, dd, 64));
        const float e = __expf(v - mx);
        float sum = e;
        for (int dd = 1; dd < 16; dd <<= 1) sum += __shfl_xor(sum, dd, 64);
        l[r] = sum;
        p2[(w * 16 + g * 4 + r) * 32 + c16] = f2bf(e);
        p2[(w * 16 + g * 4 + r) * 32 + c16 + 16] = 0;   // K pad
      }
      const s8v ap = *(const s8v*)&p2[(w * 16 + c16) * 32 + g * 8];  // same-wave RAW
      f4v o[2];
      for (int nt = 0; nt < 2; ++nt) {
        s8v bv = {0, 0, 0, 0, 0, 0, 0, 0};
        if (g < 2)
          bv = *(const s8v*)&vtG[w * 2056 + (h * 32 + nt * 16 + c16) * 16 + g * 8];
        o[nt] = MFMA16(ap, bv, fz);
      }
      for (int nt = 0; nt < 2; ++nt)
        for (int r = 0; r < 4; ++r) {
          const int d = nt * 16 + c16;
          if (d < 28) {
            const int wi = g * 4 + r;
            const int sw = (b * 32 + (wi >> 2) * 8 + y) * 32 + (wi & 3) * 8 + x;
            attn[(size_t)sw * 224 + 112 + h * 28 + d] = f2bf(o[nt][r] / l[r]);
          }
        }
    }
  }
#undef STAGE_W
}

// ---------------------------------------------------------------------------
// ws layout (bytes):
//   xb    @ 0          : 131072*224*2 = 58,720,256
//   attn  @ 58720256   : 131072*224*2 = 58,720,256
//   wqkvt @ 117440512  : 768*224*2    =    344,064
//   woutt @ 117784576  : 256*224*2    =    114,688
// ---------------------------------------------------------------------------
extern "C" void kernel_launch(void* const* d_in, const int* in_sizes, int n_in,
                              void* d_out, int out_size, void* d_ws, size_t ws_size,
                              hipStream_t stream) {
  const float* x    = (const float*)d_in[0];
  const float* Wq   = (const float*)d_in[1];
  const float* Wkv  = (const float*)d_in[2];
  const float* Wout = (const float*)d_in[3];
  const float* bout = (const float*)d_in[4];
  const float* pos1 = (const float*)d_in[5];
  const float* pos2 = (const float*)d_in[6];
  char* ws = (char*)d_ws;
  u16* xb    = (u16*)ws;
  u16* attn  = (u16*)(ws + 58720256);
  u16* wqkvt = (u16*)(ws + 117440512);
  u16* woutt = (u16*)(ws + 117784576);

  prep_kernel<<<dim3(1024), 256, 0, stream>>>(
      (const float4*)x, Wq, Wkv, Wout, xb, wqkvt, woutt);

  // fused qkv-GEMM + attention (no qkv materialization)
  attn_fused<<<dim3(4096), 256, 71680, stream>>>(xb, wqkvt, pos1, pos2, attn);

  // out = attn @ Wout + bout (f32 out, N=224 -> 2 n-tiles)
  gemm_af<1, 2><<<dim3(1024), 256, 73728, stream>>>(attn, woutt, d_out, bout, 224, 224);
}

// Round 11
// 349.100 us; speedup vs baseline: 1.1991x; 1.0480x over previous
//
#include <hip/hip_runtime.h>
#include <stdint.h>

typedef short s8v __attribute__((ext_vector_type(8)));
typedef float f4v __attribute__((ext_vector_type(4)));
typedef unsigned short u16;

#define MFMA16(a, b, c) __builtin_amdgcn_mfma_f32_16x16x32_bf16(a, b, c, 0, 0, 0)
#define SCALE 0.1889822365046136f

__device__ __forceinline__ u16 f2bf(float f) {
  union { float f; uint32_t u; } v;
  v.f = f;
  uint32_t u = v.u;
  u += 0x7fffu + ((u >> 16) & 1u);   // RNE
  return (u16)(u >> 16);
}

__device__ __forceinline__ void gld_lds16(const void* g, void* l) {
  __builtin_amdgcn_global_load_lds(
      (const __attribute__((address_space(1))) void*)g,
      (__attribute__((address_space(3))) void*)l, 16, 0, 0);
}

// ---------------------------------------------------------------------------
// prep: x f32 -> bf16 streaming cast; pack W^T for QKV (768x224, zero-padded
// rows) and Wout (256x224) as bf16 [n][k].
// ---------------------------------------------------------------------------
__global__ void prep_kernel(const float4* __restrict__ x4,
                            const float* __restrict__ Wq,
                            const float* __restrict__ Wkv,
                            const float* __restrict__ Wout,
                            u16* __restrict__ xb,
                            u16* __restrict__ wqkvt,
                            u16* __restrict__ woutt) {
  const int gsz = gridDim.x * blockDim.x;
  const int gt = blockIdx.x * blockDim.x + threadIdx.x;
  for (int i = gt; i < 7340032; i += gsz) {   // 29360128/4
    float4 v = x4[i];
    ushort4 o;
    o.x = f2bf(v.x); o.y = f2bf(v.y); o.z = f2bf(v.z); o.w = f2bf(v.w);
    ((ushort4*)xb)[i] = o;
  }
  for (int i = gt; i < 768 * 224; i += gsz) {
    const int n = i / 224, k = i - n * 224;
    float v = 0.f;
    if (n < 224) v = Wq[k * 224 + n];
    else if (n < 672) v = Wkv[k * 448 + (n - 224)];
    wqkvt[i] = f2bf(v);
  }
  for (int i = gt; i < 256 * 224; i += gsz) {
    const int n = i / 224, k = i - n * 224;
    const float v = (n < 224) ? Wout[k * 224 + n] : 0.f;
    woutt[i] = f2bf(v);
  }
}

// ---------------------------------------------------------------------------
// gemm_af (output GEMM only): C = A[M][224] * Bt^T. Unchanged.
// ---------------------------------------------------------------------------
template <int OUT_F32, int NTILES>
__global__ __launch_bounds__(256) void gemm_af(const u16* __restrict__ Ap,
                                               const u16* __restrict__ Bt,
                                               void* __restrict__ Cp,
                                               const float* __restrict__ bias,
                                               int Nvalid, int ldc) {
  extern __shared__ u16 smem[];
  u16* As  = smem;            // [128][224] = 57344 B
  u16* Bs0 = smem + 28672;
  u16* Bs1 = smem + 32768;
  const int tid = threadIdx.x;
  const int wave = tid >> 6, lane = tid & 63;
  const int c16 = lane & 15, g = lane >> 4;
  const int m0 = blockIdx.x * 128;
  const int wm = wave & 1, wn = wave >> 1;

  const int fbw = wave * 1024 + lane * 16;
  const int brow0 = fbw >> 6, bcol0 = (fbw & 63) >> 1;

#define STAGE_B(ntile, ktile, bufp)                                            \
  do {                                                                         \
    char* bb = (char*)((bufp) ? Bs1 : Bs0) + wave * 1024;                      \
    const u16* src =                                                           \
        Bt + (size_t)((ntile) * 128 + brow0) * 224 + (ktile) * 32 + bcol0;     \
    gld_lds16(src, bb);                                                        \
    gld_lds16(src + (size_t)64 * 224, bb + 4096);                              \
  } while (0)

  STAGE_B(0, 0, 0);
  if (NTILES * 7 > 1) STAGE_B(0, 1, 1);

  for (int rnd = 0; rnd < 14; ++rnd) {
    const int fb = rnd * 4096 + fbw;
    const int row = fb / 448;
    const int off = fb - row * 448;
    gld_lds16(Ap + (size_t)(m0 + row) * 224 + (off >> 1),
              (char*)As + rnd * 4096 + wave * 1024);
  }
  __syncthreads();

  for (int nt = 0; nt < NTILES; ++nt) {
    f4v acc[4][4] = {};
    for (int kt = 0; kt < 7; ++kt) {
      const int t = nt * 7 + kt;
      const u16* Bs = (t & 1) ? Bs1 : Bs0;
      s8v af[4], bf[4];
      for (int tt = 0; tt < 4; ++tt)
        af[tt] = *(const s8v*)&As[(wm * 64 + tt * 16 + c16) * 224 + kt * 32 + g * 8];
      for (int tt = 0; tt < 4; ++tt)
        bf[tt] = *(const s8v*)&Bs[(wn * 64 + tt * 16 + c16) * 32 + g * 8];
      for (int i = 0; i < 4; ++i)
        for (int j = 0; j < 4; ++j)
          acc[i][j] = MFMA16(af[i], bf[j], acc[i][j]);
      __syncthreads();
      const int ns = t + 2;
      if (ns < NTILES * 7) {
        const int nnt = ns / 7;
        STAGE_B(nnt, ns - nnt * 7, t & 1);
      }
    }
    const int n0 = nt * 128;
    for (int i = 0; i < 4; ++i) {
      const int rowb = m0 + wm * 64 + i * 16 + g * 4;
      for (int j = 0; j < 4; ++j) {
        const int col = n0 + wn * 64 + j * 16 + c16;
        if (col < Nvalid) {
          if (OUT_F32) {
            const float bz = bias[col];
            for (int r = 0; r < 4; ++r)
              ((float*)Cp)[(size_t)(rowb + r) * ldc + col] = acc[i][j][r] + bz;
          } else {
            for (int r = 0; r < 4; ++r)
              ((u16*)Cp)[(size_t)(rowb + r) * ldc + col] = f2bf(acc[i][j][r]);
          }
        }
      }
    }
  }
#undef STAGE_B
}

// ---------------------------------------------------------------------------
// FUSED qkv-GEMM + attention, R11: LDS diet -> 3 blocks/CU.
//  - Phase 1: A now STREAMED as [64][32] per-kt subtiles (dbuf) like W,
//    instead of a persistent [64][224] tile. Same bytes, same distance-2 /
//    1-barrier pipeline; phase-1 LDS 71680 -> 51200 B.
//  - Phase 2: qs/ks stride back to 32 (the stride-40 padding bought only
//    ~1.5us, R10); vtL compacted [4][28][72] (rows 28-31 were uninit garbage
//    feeding masked-out output cols; small tail over-read stays in-allocation
//    and lands only in discarded cols).
// LDS layout (u16): phase1 As0@0(2048) As1@2048 Bs0@4096(10752) Bs1@14848
//   -> 25600. phase2: qs@0[256][32] ks@8192[256][32] | local pm@0[4][64][72]
//   (18432, aliases qs+ks+gap) vtL@18432[4][28][72] | global vtG@16384
//   (w-stride 2056) p2@24608. Peak 26776 u16 -> alloc 53568 B; x3 = 160704
//   <= 163840 -> 3 blocks/CU (was 2). Occupancy is the lever.
// ---------------------------------------------------------------------------
__global__ __launch_bounds__(256, 3) void attn_fused(
    const u16* __restrict__ xb, const u16* __restrict__ Wt,
    const float* __restrict__ pos1, const float* __restrict__ pos2,
    u16* __restrict__ attn) {
  extern __shared__ u16 sm[];
  u16* As0 = sm;            // [64][32] = 2048 u16
  u16* As1 = sm + 2048;
  u16* Bs0 = sm + 4096;     // [336][32] = 10752 u16
  u16* Bs1 = sm + 14848;    // ends 25600 u16
  const int blk0 = blockIdx.x;
  const int local = (blk0 < 2048) ? 1 : 0;
  const int blk = local ? blk0 : blk0 - 2048;
  const int tid = threadIdx.x;
  const int wave = tid >> 6, lane = tid & 63;
  const int c16 = lane & 15, g = lane >> 4;
  const int b = blk >> 4, sub = blk & 15;

  int base_s = 0, ig = 0;
  if (local) {
    base_s = (b * 32 + (sub >> 2) * 8) * 32 + (sub & 3) * 8;
  } else {
    ig = sub;
  }

  // per-thread A staging address: row = tid>>2 (4 x 16B chunks per 64B row)
  int s_a;
  {
    const int arow = tid >> 2;
    if (local) {
      s_a = base_s + (arow >> 3) * 32 + (arow & 7);
    } else {
      const int w2 = arow >> 4, j = arow & 15;
      const int ii = ig * 4 + w2;
      const int y = ii >> 3, x = ii & 7;
      s_a = (b * 32 + (j >> 2) * 8 + y) * 32 + (j & 3) * 8 + x;
    }
  }
  const int a_off = (tid & 3) * 8;

#define STAGE_A(ktile, buf)                                                   \
  gld_lds16(xb + (size_t)s_a * 224 + (ktile) * 32 + a_off,                    \
            (char*)(buf) + tid * 16)

  const int qoff = local ? 0 : 112;
  // B rows 0..335 -> W^T rows {qoff..+111, 224+qoff.., 448+qoff..}
#define STAGE_W(ktile, buf)                                                   \
  do {                                                                        \
    for (int mm = 0; mm < 6; ++mm) {                                          \
      const int ch = mm * 256 + tid;                                          \
      if (ch < 1344) {                                                        \
        const int brow = ch >> 2, bc = (ch & 3) * 8;                          \
        const int n = qoff + brow + ((brow >= 112) ? 112 : 0) +               \
                      ((brow >= 224) ? 112 : 0);                              \
        gld_lds16(Wt + (size_t)n * 224 + (ktile) * 32 + bc,                   \
                  (char*)(buf) + ch * 16);                                    \
      }                                                                       \
    }                                                                         \
  } while (0)

  STAGE_A(0, As0);
  STAGE_W(0, Bs0);
  STAGE_A(1, As1);
  STAGE_W(1, Bs1);
  __syncthreads();

  // ---- mini-GEMM: acc[tile j][strip], tile = j*4+wave (<21), K = 7 steps
  f4v acc[6][4] = {};
  for (int kt = 0; kt < 7; ++kt) {
    const u16* Bs = (kt & 1) ? Bs1 : Bs0;
    const u16* Asb = (kt & 1) ? As1 : As0;
    s8v af[4];
#pragma unroll
    for (int st = 0; st < 4; ++st)
      af[st] = *(const s8v*)&Asb[(st * 16 + c16) * 32 + g * 8];
#pragma unroll
    for (int j = 0; j < 6; ++j) {
      const int tile = j * 4 + wave;
      if (tile < 21) {
        const s8v bf = *(const s8v*)&Bs[(tile * 16 + c16) * 32 + g * 8];
#pragma unroll
        for (int st = 0; st < 4; ++st)
          acc[j][st] = MFMA16(af[st], bf, acc[j][st]);
      }
    }
    __syncthreads();       // stage(kt+1) covered; buffers free; reads done
    if (kt + 2 < 7) {
      STAGE_A(kt + 2, (kt & 1) ? As1 : As0);
      STAGE_W(kt + 2, (kt & 1) ? Bs1 : Bs0);
    }
  }

  // ---- phase-2 LDS views (overlap As/Bs: dead after the final barrier)
  u16* qs  = sm;            // [256][32] = 8192 u16
  u16* ks  = sm + 8192;     // [256][32] = 8192 u16
  u16* pm  = sm;            // local P, [4][64][72] = 18432 u16 (alias qs+ks+gap)
  u16* vtL = sm + 18432;    // local [4][28][72] = 8064 u16
  u16* vtG = sm + 16384;    // global, [4] w-stride 2056 = 8224 u16
  u16* p2  = sm + 24608;    // global P, [4][16][32] = 2048 u16

  // ---- C -> LDS in attn layouts; values bit-identical to old qkv
#pragma unroll
  for (int j = 0; j < 6; ++j) {
    const int tile = j * 4 + wave;
    if (tile < 21) {
      const int seg = (tile >= 14) ? 2 : ((tile >= 7) ? 1 : 0);
      const int nn = tile * 16 + c16 - seg * 112;   // 0..111
      const int h = ((nn >= 28) ? 1 : 0) + ((nn >= 56) ? 1 : 0) + ((nn >= 84) ? 1 : 0);
      const int d = nn - h * 28;
#pragma unroll
      for (int st = 0; st < 4; ++st) {
        if (seg == 2) {      // V: 4 consecutive tokens -> one 8B store
          ushort4 o;
          o.x = f2bf(acc[j][st][0]); o.y = f2bf(acc[j][st][1]);
          o.z = f2bf(acc[j][st][2]); o.w = f2bf(acc[j][st][3]);
          if (local)
            *(ushort4*)&vtL[(h * 28 + d) * 72 + st * 16 + g * 4] = o;
          else
            *(ushort4*)&vtG[st * 2056 + (h * 32 + d) * 16 + g * 4] = o;
        } else {
          u16* dst = seg ? ks : qs;
#pragma unroll
          for (int r = 0; r < 4; ++r) {
            const u16 v = f2bf(acc[j][st][r]);
            if (local)
              dst[(h * 64 + st * 16 + g * 4 + r) * 32 + d] = v;
            else
              dst[((st * 4 + h) * 16 + g * 4 + r) * 32 + d] = v;
          }
        }
      }
    }
  }
  // zero K-pads d=28..31 of qs/ks (all 256 rows); global: vtG rows 28..31
  {
    const ushort4 z = {0, 0, 0, 0};
    *(ushort4*)(qs + tid * 32 + 28) = z;
    *(ushort4*)(ks + tid * 32 + 28) = z;
    if (!local) {
      const int w2 = tid >> 6, hq = (tid >> 4) & 3;
      const int dd = 28 + ((tid >> 2) & 3), j4 = tid & 3;
      *(ushort4*)(vtG + w2 * 2056 + (hq * 32 + dd) * 16 + j4 * 4) = z;
    }
  }
  __syncthreads();

  const f4v fz = {0.f, 0.f, 0.f, 0.f};
  if (local) {
    // ================= local attn body =================
    const int h = wave;
    s8v af2[4], bf2[4];
    for (int t = 0; t < 4; ++t)
      af2[t] = *(const s8v*)&qs[(h * 64 + t * 16 + c16) * 32 + g * 8];
    for (int t = 0; t < 4; ++t)
      bf2[t] = *(const s8v*)&ks[(h * 64 + t * 16 + c16) * 32 + g * 8];
    f4v sc[4][4];
    for (int i = 0; i < 4; ++i)
      for (int j = 0; j < 4; ++j)
        sc[i][j] = MFMA16(af2[i], bf2[j], fz);
    float lrow[4][4];
    const float* ph = pos1 + h * 4096;
    for (int i = 0; i < 4; ++i) {
      for (int r = 0; r < 4; ++r) {
        const int irow = i * 16 + g * 4 + r;
        float mx = -1e30f;
        for (int j = 0; j < 4; ++j) {
          const float v = sc[i][j][r] * SCALE + ph[irow * 64 + j * 16 + c16];
          sc[i][j][r] = v;
          mx = fmaxf(mx, v);
        }
        for (int dd = 1; dd < 16; dd <<= 1) mx = fmaxf(mx, __shfl_xor(mx, dd, 64));
        float sum = 0.f;
        for (int j = 0; j < 4; ++j) {
          const float e = __expf(sc[i][j][r] - mx);
          sc[i][j][r] = e;
          sum += e;
        }
        for (int dd = 1; dd < 16; dd <<= 1) sum += __shfl_xor(sum, dd, 64);
        lrow[i][r] = sum;
      }
    }
    __syncthreads();   // qs/ks frag reads done before pm (aliased) written
    for (int i = 0; i < 4; ++i)
      for (int r = 0; r < 4; ++r) {
        const int irow = i * 16 + g * 4 + r;
        for (int j = 0; j < 4; ++j)
          pm[(h * 64 + irow) * 72 + j * 16 + c16] = f2bf(sc[i][j][r]);
      }
    f4v o[4][2] = {};
    for (int kk = 0; kk < 2; ++kk) {
      s8v ap[4], bv[2];
      for (int t = 0; t < 4; ++t)
        ap[t] = *(const s8v*)&pm[(h * 64 + t * 16 + c16) * 72 + kk * 32 + g * 8];
      for (int t = 0; t < 2; ++t)
        bv[t] = *(const s8v*)&vtL[(h * 28 + t * 16 + c16) * 72 + kk * 32 + g * 8];
      for (int i = 0; i < 4; ++i)
        for (int j = 0; j < 2; ++j)
          o[i][j] = MFMA16(ap[i], bv[j], o[i][j]);
    }
    for (int i = 0; i < 4; ++i)
      for (int r = 0; r < 4; ++r) {
        const int irow = i * 16 + g * 4 + r;
        const int s = base_s + (irow >> 3) * 32 + (irow & 7);
        const float inv = 1.f / lrow[i][r];
        for (int j = 0; j < 2; ++j) {
          const int d = j * 16 + c16;
          if (d < 28)
            attn[(size_t)s * 224 + h * 28 + d] = f2bf(o[i][j][r] * inv);
        }
      }
  } else {
    // ================= global attn body =================
    const int w = wave;
    const int i = ig * 4 + w;
    const int y = i >> 3, x = i & 7;
    const int w4 = w * 4;
    for (int h = 0; h < 4; ++h) {
      const s8v aq = *(const s8v*)&qs[((w4 + h) * 16 + c16) * 32 + g * 8];
      const s8v bk = *(const s8v*)&ks[((w4 + h) * 16 + c16) * 32 + g * 8];
      const f4v s = MFMA16(aq, bk, fz);
      const float* ph = pos2 + h * 256;
      float l[4];
      for (int r = 0; r < 4; ++r) {
        const float v = s[r] * SCALE + ph[(g * 4 + r) * 16 + c16];
        float mx = v;
        for (int dd = 1; dd < 16; dd <<= 1) mx = fmaxf(mx, __shfl_xor(mx, dd, 64));
        const float e = __expf(v - mx);
        float sum = e;
        for (int dd = 1; dd < 16; dd <<= 1) sum += __shfl_xor(sum, dd, 64);
        l[r] = sum;
        p2[(w * 16 + g * 4 + r) * 32 + c16] = f2bf(e);
        p2[(w * 16 + g * 4 + r) * 32 + c16 + 16] = 0;   // K pad
      }
      const s8v ap = *(const s8v*)&p2[(w * 16 + c16) * 32 + g * 8];  // same-wave RAW
      f4v o[2];
      for (int nt = 0; nt < 2; ++nt) {
        s8v bv = {0, 0, 0, 0, 0, 0, 0, 0};
        if (g < 2)
          bv = *(const s8v*)&vtG[w * 2056 + (h * 32 + nt * 16 + c16) * 16 + g * 8];
        o[nt] = MFMA16(ap, bv, fz);
      }
      for (int nt = 0; nt < 2; ++nt)
        for (int r = 0; r < 4; ++r) {
          const int d = nt * 16 + c16;
          if (d < 28) {
            const int wi = g * 4 + r;
            const int sw = (b * 32 + (wi >> 2) * 8 + y) * 32 + (wi & 3) * 8 + x;
            attn[(size_t)sw * 224 + 112 + h * 28 + d] = f2bf(o[nt][r] / l[r]);
          }
        }
    }
  }
#undef STAGE_W
#undef STAGE_A
}

// ---------------------------------------------------------------------------
// ws layout (bytes):
//   xb    @ 0          : 131072*224*2 = 58,720,256
//   attn  @ 58720256   : 131072*224*2 = 58,720,256
//   wqkvt @ 117440512  : 768*224*2    =    344,064
//   woutt @ 117784576  : 256*224*2    =    114,688
// ---------------------------------------------------------------------------
extern "C" void kernel_launch(void* const* d_in, const int* in_sizes, int n_in,
                              void* d_out, int out_size, void* d_ws, size_t ws_size,
                              hipStream_t stream) {
  const float* x    = (const float*)d_in[0];
  const float* Wq   = (const float*)d_in[1];
  const float* Wkv  = (const float*)d_in[2];
  const float* Wout = (const float*)d_in[3];
  const float* bout = (const float*)d_in[4];
  const float* pos1 = (const float*)d_in[5];
  const float* pos2 = (const float*)d_in[6];
  char* ws = (char*)d_ws;
  u16* xb    = (u16*)ws;
  u16* attn  = (u16*)(ws + 58720256);
  u16* wqkvt = (u16*)(ws + 117440512);
  u16* woutt = (u16*)(ws + 117784576);

  prep_kernel<<<dim3(1024), 256, 0, stream>>>(
      (const float4*)x, Wq, Wkv, Wout, xb, wqkvt, woutt);

  // fused qkv-GEMM + attention (no qkv materialization); 53568B LDS -> 3/CU
  attn_fused<<<dim3(4096), 256, 53568, stream>>>(xb, wqkvt, pos1, pos2, attn);

  // out = attn @ Wout + bout (f32 out, N=224 -> 2 n-tiles)
  gemm_af<1, 2><<<dim3(1024), 256, 73728, stream>>>(attn, woutt, d_out, bout, 224, 224);
}